// Round 5
// baseline (166.664 us; speedup 1.0000x reference)
//
#include <hip/hip_runtime.h>

typedef __attribute__((ext_vector_type(8))) __bf16 bf16x8;
typedef __attribute__((ext_vector_type(4))) float f32x4;

__device__ __forceinline__ unsigned short f2bf(float f) {
    unsigned int u = __builtin_bit_cast(unsigned int, f);
    u = (u + 0x7FFFu + ((u >> 16) & 1u)) >> 16;
    return (unsigned short)u;
}

// ---- K0a: transpose-cast identity half (ch 0..31) to channel-last bf16 ----
__global__ void __launch_bounds__(256) prep_x1(const float* __restrict__ x,
                                               unsigned short* __restrict__ x1b) {
    int bh = blockIdx.x;                  // b*64 + h
    __shared__ unsigned short lds[64][34];
    int t = threadIdx.x;
    int w = t & 63, c4 = t >> 6;
    const float* xp = x + (size_t)(bh >> 6) * 262144 + (size_t)(bh & 63) * 64;
#pragma unroll
    for (int co = 0; co < 8; ++co) {
        int c = co * 4 + c4;
        lds[w][c] = f2bf(xp[(size_t)c * 4096 + w]);
    }
    __syncthreads();
    int wq = t >> 2, c0 = (t & 3) * 8;
    uint4 v;
    unsigned short* pv = reinterpret_cast<unsigned short*>(&v);
#pragma unroll
    for (int j = 0; j < 8; ++j) pv[j] = lds[wq][c0 + j];
    *reinterpret_cast<uint4*>(x1b + ((size_t)bh * 64 + wq) * 32 + c0) = v;
}

// ---- K0b: copy identity half f32 -> out ch 0..31 ; init objective slots ----
__global__ void __launch_bounds__(256) prep_copy(const float* __restrict__ x,
                                                 const float* __restrict__ obj,
                                                 float* __restrict__ out) {
    unsigned tid = blockIdx.x * 256 + threadIdx.x;   // 1,048,576 float4 total
    unsigned b = tid >> 15, r = tid & 32767;
    size_t off = (size_t)b * 65536 + r;
    reinterpret_cast<float4*>(out)[off] = reinterpret_cast<const float4*>(x)[off];
    if (tid < 32) out[8388608 + tid] = obj[tid];
}

// ---- K0c: repack weights to [tap][o][i] bf16 ----
__global__ void __launch_bounds__(256) prep_w(const float* __restrict__ W1,
                                              const float* __restrict__ W2,
                                              unsigned short* __restrict__ Wt1,
                                              unsigned short* __restrict__ Wt2) {
    int tid = blockIdx.x * 256 + threadIdx.x;
    if (tid < 36864) {                       // W1: [128][32][9]
        int tt = tid % 9, rem = tid / 9;
        int i = rem & 31, o = rem >> 5;
        Wt1[(tt * 128 + o) * 32 + i] = f2bf(W1[tid]);
    }
    if (tid < 110592) {                      // W2: [96][128][9]
        int tt = tid % 9, rem = tid / 9;
        int i = rem & 127, o = rem >> 7;
        Wt2[(tt * 96 + o) * 128 + i] = f2bf(W2[tid]);
    }
}

// ---- K1: conv1 (32->128 ch) + bias + ReLU -> h bf16 channel-last ----
__global__ void __launch_bounds__(256) conv1_relu(const unsigned short* __restrict__ x1b,
                                                  const float* __restrict__ b1,
                                                  const unsigned short* __restrict__ Wt1,
                                                  unsigned short* __restrict__ hbuf) {
    const int LW = 40;                          // 32 ch + 8 pad (bank spread)
    __shared__ unsigned short sx[6 * 66 * LW];  // 31,680 B
    int wg = blockIdx.x;
    int b = wg >> 4, h0 = (wg & 15) << 2;       // TH = 4 rows
    int t = threadIdx.x;

    if (t < 48) {                               // zero halo cols 0 and 65
        int row = t >> 3, k = t & 7;
        int col = (k & 1) ? 65 : 0, c0 = (k >> 1) * 8;
        *reinterpret_cast<uint4*>(&sx[(row * 66 + col) * LW + c0]) = uint4{0, 0, 0, 0};
    }
#pragma unroll
    for (int j = 0; j < 6; ++j) {               // stage 6 rows x 64 w x 32 ch
        int idx = j * 256 + t;
        int row = idx >> 8, rem = idx & 255;
        int w = rem >> 2, c0 = (rem & 3) * 8;
        int gh = h0 - 1 + row;
        uint4 v = uint4{0, 0, 0, 0};
        if (gh >= 0 && gh < 64)
            v = *reinterpret_cast<const uint4*>(x1b + (((size_t)b * 64 + gh) * 64 + w) * 32 + c0);
        *reinterpret_cast<uint4*>(&sx[(row * 66 + (w + 1)) * LW + c0]) = v;
    }
    __syncthreads();

    int wid = t >> 6, lane = t & 63;
    int lrow = lane & 15, kgrp = lane >> 4;

    bf16x8 afr[2][9];                           // hoist weights: 2 M-tiles x 9 taps
#pragma unroll
    for (int m2 = 0; m2 < 2; ++m2) {
        int o = (wid * 2 + m2) * 16 + lrow;
#pragma unroll
        for (int tap = 0; tap < 9; ++tap)
            afr[m2][tap] = *reinterpret_cast<const bf16x8*>(
                Wt1 + (size_t)(tap * 128 + o) * 32 + kgrp * 8);
    }

    for (int nt = 0; nt < 16; ++nt) {
        int r = nt >> 2, ww = ((nt & 3) << 4) + lrow;
        f32x4 acc0 = {0.f, 0.f, 0.f, 0.f}, acc1 = {0.f, 0.f, 0.f, 0.f};
#pragma unroll
        for (int dh = 0; dh < 3; ++dh)
#pragma unroll
            for (int dw = 0; dw < 3; ++dw) {
                int tap = dh * 3 + dw;
                bf16x8 bfr = *reinterpret_cast<const bf16x8*>(
                    &sx[((r + dh) * 66 + ww + dw) * LW + kgrp * 8]);
                acc0 = __builtin_amdgcn_mfma_f32_16x16x32_bf16(afr[0][tap], bfr, acc0, 0, 0, 0);
                acc1 = __builtin_amdgcn_mfma_f32_16x16x32_bf16(afr[1][tap], bfr, acc1, 0, 0, 0);
            }
        int hh = h0 + r;
        size_t obase = (((size_t)b * 64 + hh) * 64 + ww) * 128;
#pragma unroll
        for (int m2 = 0; m2 < 2; ++m2) {
            f32x4 a = (m2 == 0) ? acc0 : acc1;
            int o0 = (wid * 2 + m2) * 16 + kgrp * 4;
            unsigned short r4[4];
#pragma unroll
            for (int j = 0; j < 4; ++j) {
                float v = a[j] + b1[o0 + j];
                r4[j] = f2bf(fmaxf(v, 0.f));
            }
            uint2 pk;
            pk.x = (unsigned)r4[0] | ((unsigned)r4[1] << 16);
            pk.y = (unsigned)r4[2] | ((unsigned)r4[3] << 16);
            *reinterpret_cast<uint2*>(hbuf + obase + o0) = pk;
        }
    }
}

// ---- K2: conv2 (128->96 ch) + bias -> params (f32 LDS) -> spline -> out ----
// v5: small-acc occupancy design. TH=1 (tile 96ch x 64pos), 4 waves =
//     2 Mgrp x 2 Ngrp, acc[3][2] = 24 regs/lane. LDS 28.5 KB. f32 params.
//     XCD-contiguous block swizzle for halo L2 reuse.
__global__ void __launch_bounds__(256, 4) conv2_spline(const unsigned short* __restrict__ hbuf,
                                                       const float* __restrict__ b2,
                                                       const unsigned short* __restrict__ Wt2,
                                                       const float* __restrict__ x,
                                                       float* __restrict__ out) {
    const int LW = 72;                         // 64-ch chunk + 8 pad
    __shared__ unsigned short sx[3 * 66 * LW]; // 28,512 B (3 rows halo)
    __shared__ float red[4];
    float* pm = reinterpret_cast<float*>(sx);  // params alias [64][101] f32 = 25,856 B
    int raw = blockIdx.x;                      // 2048 blocks
    int wg = (raw & 7) * 256 + (raw >> 3);     // XCD-contiguous swizzle (bijective)
    int b = wg >> 6, h0 = wg & 63;             // TH = 1 row
    int t = threadIdx.x;
    int wid = t >> 6, lane = t & 63;
    int lrow = lane & 15, kgrp = lane >> 4;
    int mgrp = wid >> 1, ngrp = wid & 1;
    int mb = mgrp * 3;                         // wave's 3 M-tiles (48 ch)
    int nb = ngrp * 2;                         // wave's 2 N-tiles (32 pos)

    f32x4 acc[3][2];
#pragma unroll
    for (int i = 0; i < 3; ++i)
#pragma unroll
        for (int j = 0; j < 2; ++j) acc[i][j] = f32x4{0.f, 0.f, 0.f, 0.f};

    for (int kc2 = 0; kc2 < 2; ++kc2) {        // two 64-channel K chunks
        __syncthreads();
        if (t < 48) {                          // zero halo cols 0 and 65
            int row = t >> 4, k = t & 15;
            int col = (k & 1) ? 65 : 0, c0 = (k >> 1) * 8;
            *reinterpret_cast<uint4*>(&sx[(row * 66 + col) * LW + c0]) = uint4{0, 0, 0, 0};
        }
#pragma unroll
        for (int j = 0; j < 6; ++j) {          // stage 3 rows x 64 w x 64 ch
            int idx = j * 256 + t;
            int row = idx >> 9, rem = idx & 511;
            int w = rem >> 3, c0 = (rem & 7) * 8;
            int gh = h0 - 1 + row;
            uint4 v = uint4{0, 0, 0, 0};
            if (gh >= 0 && gh < 64)
                v = *reinterpret_cast<const uint4*>(
                    hbuf + (((size_t)b * 64 + gh) * 64 + w) * 128 + kc2 * 64 + c0);
            *reinterpret_cast<uint4*>(&sx[(row * 66 + (w + 1)) * LW + c0]) = v;
        }
        __syncthreads();

#pragma unroll
        for (int tap = 0; tap < 9; ++tap) {
            int dh = tap / 3, dw = tap % 3;
            bf16x8 wa[3], wb[3];
#pragma unroll
            for (int mi = 0; mi < 3; ++mi) {
                const unsigned short* wp =
                    Wt2 + (size_t)(tap * 96 + (mb + mi) * 16 + lrow) * 128 + kc2 * 64 + kgrp * 8;
                wa[mi] = *reinterpret_cast<const bf16x8*>(wp);
                wb[mi] = *reinterpret_cast<const bf16x8*>(wp + 32);
            }
#pragma unroll
            for (int ni = 0; ni < 2; ++ni) {
                int ww = nb * 16 + ni * 16 + lrow;
                int base = (dh * 66 + ww + dw) * LW;
                bf16x8 bf0 = *reinterpret_cast<const bf16x8*>(&sx[base + kgrp * 8]);
                bf16x8 bf1 = *reinterpret_cast<const bf16x8*>(&sx[base + 32 + kgrp * 8]);
#pragma unroll
                for (int mi = 0; mi < 3; ++mi) {
                    acc[mi][ni] = __builtin_amdgcn_mfma_f32_16x16x32_bf16(wa[mi], bf0, acc[mi][ni], 0, 0, 0);
                    acc[mi][ni] = __builtin_amdgcn_mfma_f32_16x16x32_bf16(wb[mi], bf1, acc[mi][ni], 0, 0, 0);
                }
            }
        }
    }
    __syncthreads();
    // params (+bias) -> LDS f32 [p][101] (odd stride: conflict-free)
#pragma unroll
    for (int mi = 0; mi < 3; ++mi) {
        int o0 = (mb + mi) * 16 + kgrp * 4;
        float bb0 = b2[o0], bb1 = b2[o0 + 1], bb2 = b2[o0 + 2], bb3 = b2[o0 + 3];
#pragma unroll
        for (int ni = 0; ni < 2; ++ni) {
            int p = (nb + ni) * 16 + lrow;
            f32x4 v = acc[mi][ni];
            pm[p * 101 + o0]     = v[0] + bb0;
            pm[p * 101 + o0 + 1] = v[1] + bb1;
            pm[p * 101 + o0 + 2] = v[2] + bb2;
            pm[p * 101 + o0 + 3] = v[3] + bb3;
        }
    }
    __syncthreads();

    // fused softmax + linear spline + identity tails + logabsdet
    float lad_acc = 0.f;
#pragma unroll 4
    for (int it = 0; it < 8; ++it) {
        int idx = it * 256 + t;                // 64 pos x 32 spline-ch
        int c = idx >> 6, p = idx & 63;
        int pb = p * 101 + 3 * c;
        float u0 = pm[pb];
        float u1 = pm[pb + 1];
        float u2 = pm[pb + 2];
        size_t gpos = (size_t)(b * 64 + 32 + c) * 4096 + (size_t)h0 * 64 + p;
        float xin = x[gpos];
        float mx = fmaxf(u0, fmaxf(u1, u2));
        float e0 = __expf(u0 - mx), e1 = __expf(u1 - mx), e2 = __expf(u2 - mx);
        float s = e0 + e1 + e2;
        float inv = 1.0f / s;
        float pos = fminf(fmaxf((xin + 1.f) * 0.5f, 0.f), 1.f) * 3.f;
        int bin = (int)pos; bin = bin > 2 ? 2 : bin;
        float alpha = pos - (float)bin;
        float eb = (bin == 0) ? e0 : ((bin == 1) ? e1 : e2);
        float cb = (bin == 0) ? 0.f : ((bin == 1) ? e0 : (e0 + e1));
        float pk = eb * inv;
        float outv = cb * inv + alpha * pk;
        outv = fminf(fmaxf(outv, 0.f), 1.f) * 2.f - 1.f;
        float lad = __logf(pk) + 1.09861228866810969f;   // + log(3)
        bool inside = (xin >= -1.f) && (xin <= 1.f);
        if (!inside) { outv = xin; lad = 0.f; }
        out[gpos] = outv;
        lad_acc += lad;
    }
#pragma unroll
    for (int off = 32; off > 0; off >>= 1)
        lad_acc += __shfl_down(lad_acc, off, 64);
    if (lane == 0) red[wid] = lad_acc;
    __syncthreads();
    if (t == 0) atomicAdd(out + 8388608 + b, red[0] + red[1] + red[2] + red[3]);
}

extern "C" void kernel_launch(void* const* d_in, const int* in_sizes, int n_in,
                              void* d_out, int out_size, void* d_ws, size_t ws_size,
                              hipStream_t stream) {
    const float* x   = (const float*)d_in[0];
    const float* obj = (const float*)d_in[1];
    const float* W1  = (const float*)d_in[2];
    const float* b1  = (const float*)d_in[3];
    const float* W2  = (const float*)d_in[4];
    const float* b2  = (const float*)d_in[5];
    float* out = (float*)d_out;
    char* ws = (char*)d_ws;

    unsigned short* x1b  = (unsigned short*)ws;                          //  8,388,608 B
    unsigned short* hbuf = (unsigned short*)(ws + 8388608);              // 33,554,432 B
    unsigned short* Wt1  = (unsigned short*)(ws + 8388608 + 33554432);   //     73,728 B
    unsigned short* Wt2  = (unsigned short*)(ws + 8388608 + 33554432 + 73728); // 221,184 B

    hipLaunchKernelGGL(prep_x1,      dim3(2048), dim3(256), 0, stream, x, x1b);
    hipLaunchKernelGGL(prep_copy,    dim3(4096), dim3(256), 0, stream, x, obj, out);
    hipLaunchKernelGGL(prep_w,       dim3(432),  dim3(256), 0, stream, W1, W2, Wt1, Wt2);
    hipLaunchKernelGGL(conv1_relu,   dim3(512),  dim3(256), 0, stream, x1b, b1, Wt1, hbuf);
    hipLaunchKernelGGL(conv2_spline, dim3(2048), dim3(256), 0, stream, hbuf, b2, Wt2, x, out);
}

// Round 7
// 158.241 us; speedup vs baseline: 1.0532x; 1.0532x over previous
//
#include <hip/hip_runtime.h>

typedef __attribute__((ext_vector_type(8))) __bf16 bf16x8;
typedef __attribute__((ext_vector_type(4))) float f32x4;

__device__ __forceinline__ unsigned short f2bf(float f) {
    unsigned int u = __builtin_bit_cast(unsigned int, f);
    u = (u + 0x7FFFu + ((u >> 16) & 1u)) >> 16;
    return (unsigned short)u;
}

// ---- K0a: transpose-cast identity half (ch 0..31) to channel-last bf16 ----
__global__ void __launch_bounds__(256) prep_x1(const float* __restrict__ x,
                                               unsigned short* __restrict__ x1b) {
    int bh = blockIdx.x;                  // b*64 + h
    __shared__ unsigned short lds[64][34];
    int t = threadIdx.x;
    int w = t & 63, c4 = t >> 6;
    const float* xp = x + (size_t)(bh >> 6) * 262144 + (size_t)(bh & 63) * 64;
#pragma unroll
    for (int co = 0; co < 8; ++co) {
        int c = co * 4 + c4;
        lds[w][c] = f2bf(xp[(size_t)c * 4096 + w]);
    }
    __syncthreads();
    int wq = t >> 2, c0 = (t & 3) * 8;
    uint4 v;
    unsigned short* pv = reinterpret_cast<unsigned short*>(&v);
#pragma unroll
    for (int j = 0; j < 8; ++j) pv[j] = lds[wq][c0 + j];
    *reinterpret_cast<uint4*>(x1b + ((size_t)bh * 64 + wq) * 32 + c0) = v;
}

// ---- K0b: copy identity half f32 -> out ch 0..31 ; init objective slots ----
__global__ void __launch_bounds__(256) prep_copy(const float* __restrict__ x,
                                                 const float* __restrict__ obj,
                                                 float* __restrict__ out) {
    unsigned tid = blockIdx.x * 256 + threadIdx.x;   // 1,048,576 float4 total
    unsigned b = tid >> 15, r = tid & 32767;
    size_t off = (size_t)b * 65536 + r;
    reinterpret_cast<float4*>(out)[off] = reinterpret_cast<const float4*>(x)[off];
    if (tid < 32) out[8388608 + tid] = obj[tid];
}

// ---- K0c: repack weights to [tap][o][i] bf16 ----
__global__ void __launch_bounds__(256) prep_w(const float* __restrict__ W1,
                                              const float* __restrict__ W2,
                                              unsigned short* __restrict__ Wt1,
                                              unsigned short* __restrict__ Wt2) {
    int tid = blockIdx.x * 256 + threadIdx.x;
    if (tid < 36864) {                       // W1: [128][32][9]
        int tt = tid % 9, rem = tid / 9;
        int i = rem & 31, o = rem >> 5;
        Wt1[(tt * 128 + o) * 32 + i] = f2bf(W1[tid]);
    }
    if (tid < 110592) {                      // W2: [96][128][9]
        int tt = tid % 9, rem = tid / 9;
        int i = rem & 127, o = rem >> 7;
        Wt2[(tt * 96 + o) * 128 + i] = f2bf(W2[tid]);
    }
}

// ---- K1: conv1 (32->128 ch) + bias + ReLU -> h bf16 channel-last ----
__global__ void __launch_bounds__(256) conv1_relu(const unsigned short* __restrict__ x1b,
                                                  const float* __restrict__ b1,
                                                  const unsigned short* __restrict__ Wt1,
                                                  unsigned short* __restrict__ hbuf) {
    const int LW = 40;                          // 32 ch + 8 pad (bank spread)
    __shared__ unsigned short sx[6 * 66 * LW];  // 31,680 B
    int wg = blockIdx.x;
    int b = wg >> 4, h0 = (wg & 15) << 2;       // TH = 4 rows
    int t = threadIdx.x;

    if (t < 48) {                               // zero halo cols 0 and 65
        int row = t >> 3, k = t & 7;
        int col = (k & 1) ? 65 : 0, c0 = (k >> 1) * 8;
        *reinterpret_cast<uint4*>(&sx[(row * 66 + col) * LW + c0]) = uint4{0, 0, 0, 0};
    }
#pragma unroll
    for (int j = 0; j < 6; ++j) {               // stage 6 rows x 64 w x 32 ch
        int idx = j * 256 + t;
        int row = idx >> 8, rem = idx & 255;
        int w = rem >> 2, c0 = (rem & 3) * 8;
        int gh = h0 - 1 + row;
        uint4 v = uint4{0, 0, 0, 0};
        if (gh >= 0 && gh < 64)
            v = *reinterpret_cast<const uint4*>(x1b + (((size_t)b * 64 + gh) * 64 + w) * 32 + c0);
        *reinterpret_cast<uint4*>(&sx[(row * 66 + (w + 1)) * LW + c0]) = v;
    }
    __syncthreads();

    int wid = t >> 6, lane = t & 63;
    int lrow = lane & 15, kgrp = lane >> 4;

    bf16x8 afr[2][9];                           // hoist weights: 2 M-tiles x 9 taps
#pragma unroll
    for (int m2 = 0; m2 < 2; ++m2) {
        int o = (wid * 2 + m2) * 16 + lrow;
#pragma unroll
        for (int tap = 0; tap < 9; ++tap)
            afr[m2][tap] = *reinterpret_cast<const bf16x8*>(
                Wt1 + (size_t)(tap * 128 + o) * 32 + kgrp * 8);
    }

    for (int nt = 0; nt < 16; ++nt) {
        int r = nt >> 2, ww = ((nt & 3) << 4) + lrow;
        f32x4 acc0 = {0.f, 0.f, 0.f, 0.f}, acc1 = {0.f, 0.f, 0.f, 0.f};
#pragma unroll
        for (int dh = 0; dh < 3; ++dh)
#pragma unroll
            for (int dw = 0; dw < 3; ++dw) {
                int tap = dh * 3 + dw;
                bf16x8 bfr = *reinterpret_cast<const bf16x8*>(
                    &sx[((r + dh) * 66 + ww + dw) * LW + kgrp * 8]);
                acc0 = __builtin_amdgcn_mfma_f32_16x16x32_bf16(afr[0][tap], bfr, acc0, 0, 0, 0);
                acc1 = __builtin_amdgcn_mfma_f32_16x16x32_bf16(afr[1][tap], bfr, acc1, 0, 0, 0);
            }
        int hh = h0 + r;
        size_t obase = (((size_t)b * 64 + hh) * 64 + ww) * 128;
#pragma unroll
        for (int m2 = 0; m2 < 2; ++m2) {
            f32x4 a = (m2 == 0) ? acc0 : acc1;
            int o0 = (wid * 2 + m2) * 16 + kgrp * 4;
            unsigned short r4[4];
#pragma unroll
            for (int j = 0; j < 4; ++j) {
                float v = a[j] + b1[o0 + j];
                r4[j] = f2bf(fmaxf(v, 0.f));
            }
            uint2 pk;
            pk.x = (unsigned)r4[0] | ((unsigned)r4[1] << 16);
            pk.y = (unsigned)r4[2] | ((unsigned)r4[3] << 16);
            *reinterpret_cast<uint2*>(hbuf + obase + o0) = pk;
        }
    }
}

// ---- K2: conv2 (128->96 ch) + bias -> params (f32 LDS) -> spline -> out ----
// v6: identical to v5 but NO min-waves launch bound — r4/r5 showed
//     __launch_bounds__(256,4) clamps arch VGPRs to 64 and spills ~75 MB
//     to scratch. Natural usage ~114 unified -> 128 bucket -> 16 waves/CU.
__global__ void __launch_bounds__(256) conv2_spline(const unsigned short* __restrict__ hbuf,
                                                    const float* __restrict__ b2,
                                                    const unsigned short* __restrict__ Wt2,
                                                    const float* __restrict__ x,
                                                    float* __restrict__ out) {
    const int LW = 72;                         // 64-ch chunk + 8 pad
    __shared__ unsigned short sx[3 * 66 * LW]; // 28,512 B (3 rows halo)
    __shared__ float red[4];
    float* pm = reinterpret_cast<float*>(sx);  // params alias [64][101] f32 = 25,856 B
    int raw = blockIdx.x;                      // 2048 blocks
    int wg = (raw & 7) * 256 + (raw >> 3);     // XCD-contiguous swizzle (bijective)
    int b = wg >> 6, h0 = wg & 63;             // TH = 1 row
    int t = threadIdx.x;
    int wid = t >> 6, lane = t & 63;
    int lrow = lane & 15, kgrp = lane >> 4;
    int mgrp = wid >> 1, ngrp = wid & 1;
    int mb = mgrp * 3;                         // wave's 3 M-tiles (48 ch)
    int nb = ngrp * 2;                         // wave's 2 N-tiles (32 pos)

    f32x4 acc[3][2];
#pragma unroll
    for (int i = 0; i < 3; ++i)
#pragma unroll
        for (int j = 0; j < 2; ++j) acc[i][j] = f32x4{0.f, 0.f, 0.f, 0.f};

    for (int kc2 = 0; kc2 < 2; ++kc2) {        // two 64-channel K chunks
        __syncthreads();
        if (t < 48) {                          // zero halo cols 0 and 65
            int row = t >> 4, k = t & 15;
            int col = (k & 1) ? 65 : 0, c0 = (k >> 1) * 8;
            *reinterpret_cast<uint4*>(&sx[(row * 66 + col) * LW + c0]) = uint4{0, 0, 0, 0};
        }
#pragma unroll
        for (int j = 0; j < 6; ++j) {          // stage 3 rows x 64 w x 64 ch
            int idx = j * 256 + t;
            int row = idx >> 9, rem = idx & 511;
            int w = rem >> 3, c0 = (rem & 7) * 8;
            int gh = h0 - 1 + row;
            uint4 v = uint4{0, 0, 0, 0};
            if (gh >= 0 && gh < 64)
                v = *reinterpret_cast<const uint4*>(
                    hbuf + (((size_t)b * 64 + gh) * 64 + w) * 128 + kc2 * 64 + c0);
            *reinterpret_cast<uint4*>(&sx[(row * 66 + (w + 1)) * LW + c0]) = v;
        }
        __syncthreads();

#pragma unroll
        for (int tap = 0; tap < 9; ++tap) {
            int dh = tap / 3, dw = tap % 3;
            bf16x8 wa[3], wb[3];
#pragma unroll
            for (int mi = 0; mi < 3; ++mi) {
                const unsigned short* wp =
                    Wt2 + (size_t)(tap * 96 + (mb + mi) * 16 + lrow) * 128 + kc2 * 64 + kgrp * 8;
                wa[mi] = *reinterpret_cast<const bf16x8*>(wp);
                wb[mi] = *reinterpret_cast<const bf16x8*>(wp + 32);
            }
#pragma unroll
            for (int ni = 0; ni < 2; ++ni) {
                int ww = nb * 16 + ni * 16 + lrow;
                int base = (dh * 66 + ww + dw) * LW;
                bf16x8 bf0 = *reinterpret_cast<const bf16x8*>(&sx[base + kgrp * 8]);
                bf16x8 bf1 = *reinterpret_cast<const bf16x8*>(&sx[base + 32 + kgrp * 8]);
#pragma unroll
                for (int mi = 0; mi < 3; ++mi) {
                    acc[mi][ni] = __builtin_amdgcn_mfma_f32_16x16x32_bf16(wa[mi], bf0, acc[mi][ni], 0, 0, 0);
                    acc[mi][ni] = __builtin_amdgcn_mfma_f32_16x16x32_bf16(wb[mi], bf1, acc[mi][ni], 0, 0, 0);
                }
            }
        }
    }
    __syncthreads();
    // params (+bias) -> LDS f32 [p][101] (odd stride: conflict-free)
#pragma unroll
    for (int mi = 0; mi < 3; ++mi) {
        int o0 = (mb + mi) * 16 + kgrp * 4;
        float bb0 = b2[o0], bb1 = b2[o0 + 1], bb2 = b2[o0 + 2], bb3 = b2[o0 + 3];
#pragma unroll
        for (int ni = 0; ni < 2; ++ni) {
            int p = (nb + ni) * 16 + lrow;
            f32x4 v = acc[mi][ni];
            pm[p * 101 + o0]     = v[0] + bb0;
            pm[p * 101 + o0 + 1] = v[1] + bb1;
            pm[p * 101 + o0 + 2] = v[2] + bb2;
            pm[p * 101 + o0 + 3] = v[3] + bb3;
        }
    }
    __syncthreads();

    // fused softmax + linear spline + identity tails + logabsdet
    float lad_acc = 0.f;
#pragma unroll 4
    for (int it = 0; it < 8; ++it) {
        int idx = it * 256 + t;                // 64 pos x 32 spline-ch
        int c = idx >> 6, p = idx & 63;
        int pb = p * 101 + 3 * c;
        float u0 = pm[pb];
        float u1 = pm[pb + 1];
        float u2 = pm[pb + 2];
        size_t gpos = (size_t)(b * 64 + 32 + c) * 4096 + (size_t)h0 * 64 + p;
        float xin = x[gpos];
        float mx = fmaxf(u0, fmaxf(u1, u2));
        float e0 = __expf(u0 - mx), e1 = __expf(u1 - mx), e2 = __expf(u2 - mx);
        float s = e0 + e1 + e2;
        float inv = 1.0f / s;
        float pos = fminf(fmaxf((xin + 1.f) * 0.5f, 0.f), 1.f) * 3.f;
        int bin = (int)pos; bin = bin > 2 ? 2 : bin;
        float alpha = pos - (float)bin;
        float eb = (bin == 0) ? e0 : ((bin == 1) ? e1 : e2);
        float cb = (bin == 0) ? 0.f : ((bin == 1) ? e0 : (e0 + e1));
        float pk = eb * inv;
        float outv = cb * inv + alpha * pk;
        outv = fminf(fmaxf(outv, 0.f), 1.f) * 2.f - 1.f;
        float lad = __logf(pk) + 1.09861228866810969f;   // + log(3)
        bool inside = (xin >= -1.f) && (xin <= 1.f);
        if (!inside) { outv = xin; lad = 0.f; }
        out[gpos] = outv;
        lad_acc += lad;
    }
#pragma unroll
    for (int off = 32; off > 0; off >>= 1)
        lad_acc += __shfl_down(lad_acc, off, 64);
    if (lane == 0) red[wid] = lad_acc;
    __syncthreads();
    if (t == 0) atomicAdd(out + 8388608 + b, red[0] + red[1] + red[2] + red[3]);
}

extern "C" void kernel_launch(void* const* d_in, const int* in_sizes, int n_in,
                              void* d_out, int out_size, void* d_ws, size_t ws_size,
                              hipStream_t stream) {
    const float* x   = (const float*)d_in[0];
    const float* obj = (const float*)d_in[1];
    const float* W1  = (const float*)d_in[2];
    const float* b1  = (const float*)d_in[3];
    const float* W2  = (const float*)d_in[4];
    const float* b2  = (const float*)d_in[5];
    float* out = (float*)d_out;
    char* ws = (char*)d_ws;

    unsigned short* x1b  = (unsigned short*)ws;                          //  8,388,608 B
    unsigned short* hbuf = (unsigned short*)(ws + 8388608);              // 33,554,432 B
    unsigned short* Wt1  = (unsigned short*)(ws + 8388608 + 33554432);   //     73,728 B
    unsigned short* Wt2  = (unsigned short*)(ws + 8388608 + 33554432 + 73728); // 221,184 B

    hipLaunchKernelGGL(prep_x1,      dim3(2048), dim3(256), 0, stream, x, x1b);
    hipLaunchKernelGGL(prep_copy,    dim3(4096), dim3(256), 0, stream, x, obj, out);
    hipLaunchKernelGGL(prep_w,       dim3(432),  dim3(256), 0, stream, W1, W2, Wt1, Wt2);
    hipLaunchKernelGGL(conv1_relu,   dim3(512),  dim3(256), 0, stream, x1b, b1, Wt1, hbuf);
    hipLaunchKernelGGL(conv2_spline, dim3(2048), dim3(256), 0, stream, hbuf, b2, Wt2, x, out);
}

// Round 8
// 91.231 us; speedup vs baseline: 1.8268x; 1.7345x over previous
//
#include <hip/hip_runtime.h>

typedef __attribute__((ext_vector_type(8))) __bf16 bf16x8;
typedef __attribute__((ext_vector_type(4))) float f32x4;

__device__ __forceinline__ unsigned short f2bf(float f) {
    unsigned int u = __builtin_bit_cast(unsigned int, f);
    u = (u + 0x7FFFu + ((u >> 16) & 1u)) >> 16;
    return (unsigned short)u;
}

// ---- K0a: transpose-cast identity half (ch 0..31) to channel-last bf16 ----
__global__ void __launch_bounds__(256) prep_x1(const float* __restrict__ x,
                                               unsigned short* __restrict__ x1b) {
    int bh = blockIdx.x;                  // b*64 + h
    __shared__ unsigned short lds[64][34];
    int t = threadIdx.x;
    int w = t & 63, c4 = t >> 6;
    const float* xp = x + (size_t)(bh >> 6) * 262144 + (size_t)(bh & 63) * 64;
#pragma unroll
    for (int co = 0; co < 8; ++co) {
        int c = co * 4 + c4;
        lds[w][c] = f2bf(xp[(size_t)c * 4096 + w]);
    }
    __syncthreads();
    int wq = t >> 2, c0 = (t & 3) * 8;
    uint4 v;
    unsigned short* pv = reinterpret_cast<unsigned short*>(&v);
#pragma unroll
    for (int j = 0; j < 8; ++j) pv[j] = lds[wq][c0 + j];
    *reinterpret_cast<uint4*>(x1b + ((size_t)bh * 64 + wq) * 32 + c0) = v;
}

// ---- K0b: copy identity half f32 -> out ch 0..31 ; init objective slots ----
__global__ void __launch_bounds__(256) prep_copy(const float* __restrict__ x,
                                                 const float* __restrict__ obj,
                                                 float* __restrict__ out) {
    unsigned tid = blockIdx.x * 256 + threadIdx.x;   // 1,048,576 float4 total
    unsigned b = tid >> 15, r = tid & 32767;
    size_t off = (size_t)b * 65536 + r;
    reinterpret_cast<float4*>(out)[off] = reinterpret_cast<const float4*>(x)[off];
    if (tid < 32) out[8388608 + tid] = obj[tid];
}

// ---- K0c: repack weights. Wt1: [tap][o][i].  Wt2: [kc][tap][96][64] ----
__global__ void __launch_bounds__(256) prep_w(const float* __restrict__ W1,
                                              const float* __restrict__ W2,
                                              unsigned short* __restrict__ Wt1,
                                              unsigned short* __restrict__ Wt2) {
    int tid = blockIdx.x * 256 + threadIdx.x;
    if (tid < 36864) {                       // W1: [128][32][9]
        int tt = tid % 9, rem = tid / 9;
        int i = rem & 31, o = rem >> 5;
        Wt1[(tt * 128 + o) * 32 + i] = f2bf(W1[tid]);
    }
    if (tid < 110592) {                      // W2: [96][128][9] -> [kc][tap][o][i%64]
        int tt = tid % 9, rem = tid / 9;
        int i = rem & 127, o = rem >> 7;
        int kc = i >> 6, ii = i & 63;
        Wt2[(((kc * 9 + tt) * 96 + o) * 64) + ii] = f2bf(W2[tid]);
    }
}

// ---- K1: conv1 (32->128 ch) + bias + ReLU -> h bf16 channel-last ----
__global__ void __launch_bounds__(256) conv1_relu(const unsigned short* __restrict__ x1b,
                                                  const float* __restrict__ b1,
                                                  const unsigned short* __restrict__ Wt1,
                                                  unsigned short* __restrict__ hbuf) {
    const int LW = 40;                          // 32 ch + 8 pad (bank spread)
    __shared__ unsigned short sx[6 * 66 * LW];  // 31,680 B
    int wg = blockIdx.x;
    int b = wg >> 4, h0 = (wg & 15) << 2;       // TH = 4 rows
    int t = threadIdx.x;

    if (t < 48) {                               // zero halo cols 0 and 65
        int row = t >> 3, k = t & 7;
        int col = (k & 1) ? 65 : 0, c0 = (k >> 1) * 8;
        *reinterpret_cast<uint4*>(&sx[(row * 66 + col) * LW + c0]) = uint4{0, 0, 0, 0};
    }
#pragma unroll
    for (int j = 0; j < 6; ++j) {               // stage 6 rows x 64 w x 32 ch
        int idx = j * 256 + t;
        int row = idx >> 8, rem = idx & 255;
        int w = rem >> 2, c0 = (rem & 3) * 8;
        int gh = h0 - 1 + row;
        uint4 v = uint4{0, 0, 0, 0};
        if (gh >= 0 && gh < 64)
            v = *reinterpret_cast<const uint4*>(x1b + (((size_t)b * 64 + gh) * 64 + w) * 32 + c0);
        *reinterpret_cast<uint4*>(&sx[(row * 66 + (w + 1)) * LW + c0]) = v;
    }
    __syncthreads();

    int wid = t >> 6, lane = t & 63;
    int lrow = lane & 15, kgrp = lane >> 4;

    bf16x8 afr[2][9];                           // hoist weights: 2 M-tiles x 9 taps
#pragma unroll
    for (int m2 = 0; m2 < 2; ++m2) {
        int o = (wid * 2 + m2) * 16 + lrow;
#pragma unroll
        for (int tap = 0; tap < 9; ++tap)
            afr[m2][tap] = *reinterpret_cast<const bf16x8*>(
                Wt1 + (size_t)(tap * 128 + o) * 32 + kgrp * 8);
    }

    for (int nt = 0; nt < 16; ++nt) {
        int r = nt >> 2, ww = ((nt & 3) << 4) + lrow;
        f32x4 acc0 = {0.f, 0.f, 0.f, 0.f}, acc1 = {0.f, 0.f, 0.f, 0.f};
#pragma unroll
        for (int dh = 0; dh < 3; ++dh)
#pragma unroll
            for (int dw = 0; dw < 3; ++dw) {
                int tap = dh * 3 + dw;
                bf16x8 bfr = *reinterpret_cast<const bf16x8*>(
                    &sx[((r + dh) * 66 + ww + dw) * LW + kgrp * 8]);
                acc0 = __builtin_amdgcn_mfma_f32_16x16x32_bf16(afr[0][tap], bfr, acc0, 0, 0, 0);
                acc1 = __builtin_amdgcn_mfma_f32_16x16x32_bf16(afr[1][tap], bfr, acc1, 0, 0, 0);
            }
        int hh = h0 + r;
        size_t obase = (((size_t)b * 64 + hh) * 64 + ww) * 128;
#pragma unroll
        for (int m2 = 0; m2 < 2; ++m2) {
            f32x4 a = (m2 == 0) ? acc0 : acc1;
            int o0 = (wid * 2 + m2) * 16 + kgrp * 4;
            unsigned short r4[4];
#pragma unroll
            for (int j = 0; j < 4; ++j) {
                float v = a[j] + b1[o0 + j];
                r4[j] = f2bf(fmaxf(v, 0.f));
            }
            uint2 pk;
            pk.x = (unsigned)r4[0] | ((unsigned)r4[1] << 16);
            pk.y = (unsigned)r4[2] | ((unsigned)r4[3] << 16);
            *reinterpret_cast<uint2*>(hbuf + obase + o0) = pk;
        }
    }
}

// ---- K2 v8: conv2 as LDS-staged GEMM. 512 thr, tile 96 out x 256 pos (TH=4).
//      Weights cooperatively staged to LDS per (chunk, tap) -> all waves read
//      fragments from LDS, nothing tap-serial goes to L2. 512 blocks (2/CU).
__global__ void __launch_bounds__(512) conv2_spline(const unsigned short* __restrict__ hbuf,
                                                    const float* __restrict__ b2,
                                                    const unsigned short* __restrict__ Wt2,
                                                    const float* __restrict__ x,
                                                    float* __restrict__ out) {
    const int LWA = 72;                          // act: 64 ch + 8 pad
    const int LWW = 72;                          // wgt: 64 ch + 8 pad (odd 16B-slot stride)
    __shared__ unsigned short sa[6 * 66 * LWA];  // 57,024 B act (6 rows incl halo)
    __shared__ unsigned short sw[96 * LWW];      // 13,824 B weights [96 out][64 ch]
    __shared__ float red[8];
    float* pm = reinterpret_cast<float*>(sa);    // params alias [128][101] f32 = 51,712 B

    int raw = blockIdx.x;                        // 512 blocks
    int wg = (raw & 7) * 64 + (raw >> 3);        // XCD-contiguous swizzle (bijective)
    int b = wg >> 4, h0 = (wg & 15) << 2;        // TH = 4 rows
    int t = threadIdx.x;
    int wid = t >> 6, lane = t & 63;
    int lrow = lane & 15, kgrp = lane >> 4;
    int mgrp = wid >> 2, ngrp = wid & 3;         // 2 Mgrp x 4 Ngrp
    int mb = mgrp * 3;                           // 3 M-tiles (48 ch) per wave

    f32x4 acc[3][4];
#pragma unroll
    for (int i = 0; i < 3; ++i)
#pragma unroll
        for (int j = 0; j < 4; ++j) acc[i][j] = f32x4{0.f, 0.f, 0.f, 0.f};

    for (int kc2 = 0; kc2 < 2; ++kc2) {          // two 64-channel K chunks
        __syncthreads();                         // act buffer free
        // stage act: rows h0-1..h0+4, 64 w, 64 ch  (3072 uint4)
#pragma unroll
        for (int j = 0; j < 6; ++j) {
            int idx = j * 512 + t;
            int row = idx >> 9, rem = idx & 511;
            int w = rem >> 3, c0 = (rem & 7) * 8;
            int gh = h0 - 1 + row;
            uint4 v = uint4{0, 0, 0, 0};
            if (gh >= 0 && gh < 64)
                v = *reinterpret_cast<const uint4*>(
                    hbuf + (((size_t)b * 64 + gh) * 64 + w) * 128 + kc2 * 64 + c0);
            *reinterpret_cast<uint4*>(&sa[(row * 66 + (w + 1)) * LWA + c0]) = v;
        }
        if (t < 96) {                            // zero halo cols 0 and 65 (6 rows x 2 x 8grp)
            int row = t >> 4, k = t & 15;
            int col = (k & 1) ? 65 : 0, c0 = (k >> 1) * 8;
            *reinterpret_cast<uint4*>(&sa[(row * 66 + col) * LWA + c0]) = uint4{0, 0, 0, 0};
        }

        for (int tap = 0; tap < 9; ++tap) {
            __syncthreads();                     // prev-tap weight reads done (tap0: also act-stage fence pt.1)
            // stage weights [96][64] for (kc2, tap): 768 uint4 by 512 threads
            {
                const unsigned short* wsrc = Wt2 + (size_t)((kc2 * 9 + tap) * 96) * 64;
                uint4 v = *reinterpret_cast<const uint4*>(wsrc + t * 8);
                *reinterpret_cast<uint4*>(&sw[(t >> 3) * LWW + (t & 7) * 8]) = v;
                if (t < 256) {
                    int f = 512 + t;
                    uint4 v2 = *reinterpret_cast<const uint4*>(wsrc + f * 8);
                    *reinterpret_cast<uint4*>(&sw[(f >> 3) * LWW + (f & 7) * 8]) = v2;
                }
            }
            __syncthreads();                     // weights staged (+ act staged, on tap0)
            int dh = tap / 3, dw = tap % 3;
            bf16x8 wfr[3][2];
#pragma unroll
            for (int mi = 0; mi < 3; ++mi) {
                int o = (mb + mi) * 16 + lrow;
                wfr[mi][0] = *reinterpret_cast<const bf16x8*>(&sw[o * LWW + kgrp * 8]);
                wfr[mi][1] = *reinterpret_cast<const bf16x8*>(&sw[o * LWW + 32 + kgrp * 8]);
            }
#pragma unroll
            for (int ni = 0; ni < 4; ++ni) {
                int nt = ngrp * 4 + ni;          // 0..15 -> pos nt*16+lrow
                int rr = nt >> 2, wcol = (nt & 3) * 16 + lrow;
                int base = ((rr + dh) * 66 + wcol + dw) * LWA;
                bf16x8 a0 = *reinterpret_cast<const bf16x8*>(&sa[base + kgrp * 8]);
                bf16x8 a1 = *reinterpret_cast<const bf16x8*>(&sa[base + 32 + kgrp * 8]);
#pragma unroll
                for (int mi = 0; mi < 3; ++mi) {
                    acc[mi][ni] = __builtin_amdgcn_mfma_f32_16x16x32_bf16(wfr[mi][0], a0, acc[mi][ni], 0, 0, 0);
                    acc[mi][ni] = __builtin_amdgcn_mfma_f32_16x16x32_bf16(wfr[mi][1], a1, acc[mi][ni], 0, 0, 0);
                }
            }
        }
    }

    // ---- epilogue: two 128-position halves (params f32 aliased over act) ----
    float lad_acc = 0.f;
    for (int half = 0; half < 2; ++half) {
        __syncthreads();                         // acc done / prev-half spline reads done
        if ((ngrp >> 1) == half) {               // ngrp {0,1}->half0, {2,3}->half1
#pragma unroll
            for (int mi = 0; mi < 3; ++mi) {
                int o0 = (mb + mi) * 16 + kgrp * 4;
                float bb0 = b2[o0], bb1 = b2[o0 + 1], bb2 = b2[o0 + 2], bb3 = b2[o0 + 3];
#pragma unroll
                for (int ni = 0; ni < 4; ++ni) {
                    int p = (ngrp & 1) * 64 + ni * 16 + lrow;   // 0..127 within half
                    f32x4 v = acc[mi][ni];
                    pm[p * 101 + o0]     = v[0] + bb0;
                    pm[p * 101 + o0 + 1] = v[1] + bb1;
                    pm[p * 101 + o0 + 2] = v[2] + bb2;
                    pm[p * 101 + o0 + 3] = v[3] + bb3;
                }
            }
        }
        __syncthreads();
        // spline: 128 pos x 32 spline-ch = 4096 elems, 512 thr x 8 iters
#pragma unroll 4
        for (int it = 0; it < 8; ++it) {
            int idx = it * 512 + t;
            int c = idx >> 7, p = idx & 127;
            int pos = half * 128 + p;
            int pb = p * 101 + 3 * c;
            float u0 = pm[pb];
            float u1 = pm[pb + 1];
            float u2 = pm[pb + 2];
            size_t gpos = (size_t)(b * 64 + 32 + c) * 4096 + (size_t)(h0 + (pos >> 6)) * 64 + (pos & 63);
            float xin = x[gpos];
            float mx = fmaxf(u0, fmaxf(u1, u2));
            float e0 = __expf(u0 - mx), e1 = __expf(u1 - mx), e2 = __expf(u2 - mx);
            float s = e0 + e1 + e2;
            float inv = 1.0f / s;
            float pos01 = fminf(fmaxf((xin + 1.f) * 0.5f, 0.f), 1.f) * 3.f;
            int bin = (int)pos01; bin = bin > 2 ? 2 : bin;
            float alpha = pos01 - (float)bin;
            float eb = (bin == 0) ? e0 : ((bin == 1) ? e1 : e2);
            float cb = (bin == 0) ? 0.f : ((bin == 1) ? e0 : (e0 + e1));
            float pk = eb * inv;
            float outv = cb * inv + alpha * pk;
            outv = fminf(fmaxf(outv, 0.f), 1.f) * 2.f - 1.f;
            float lad = __logf(pk) + 1.09861228866810969f;   // + log(3)
            bool inside = (xin >= -1.f) && (xin <= 1.f);
            if (!inside) { outv = xin; lad = 0.f; }
            out[gpos] = outv;
            lad_acc += lad;
        }
    }
#pragma unroll
    for (int off = 32; off > 0; off >>= 1)
        lad_acc += __shfl_down(lad_acc, off, 64);
    if (lane == 0) red[wid] = lad_acc;
    __syncthreads();
    if (t == 0) {
        float s = 0.f;
#pragma unroll
        for (int i = 0; i < 8; ++i) s += red[i];
        atomicAdd(out + 8388608 + b, s);
    }
}

extern "C" void kernel_launch(void* const* d_in, const int* in_sizes, int n_in,
                              void* d_out, int out_size, void* d_ws, size_t ws_size,
                              hipStream_t stream) {
    const float* x   = (const float*)d_in[0];
    const float* obj = (const float*)d_in[1];
    const float* W1  = (const float*)d_in[2];
    const float* b1  = (const float*)d_in[3];
    const float* W2  = (const float*)d_in[4];
    const float* b2  = (const float*)d_in[5];
    float* out = (float*)d_out;
    char* ws = (char*)d_ws;

    unsigned short* x1b  = (unsigned short*)ws;                          //  8,388,608 B
    unsigned short* hbuf = (unsigned short*)(ws + 8388608);              // 33,554,432 B
    unsigned short* Wt1  = (unsigned short*)(ws + 8388608 + 33554432);   //     73,728 B
    unsigned short* Wt2  = (unsigned short*)(ws + 8388608 + 33554432 + 73728); // 221,184 B

    hipLaunchKernelGGL(prep_x1,      dim3(2048), dim3(256), 0, stream, x, x1b);
    hipLaunchKernelGGL(prep_copy,    dim3(4096), dim3(256), 0, stream, x, obj, out);
    hipLaunchKernelGGL(prep_w,       dim3(432),  dim3(256), 0, stream, W1, W2, Wt1, Wt2);
    hipLaunchKernelGGL(conv1_relu,   dim3(512),  dim3(256), 0, stream, x1b, b1, Wt1, hbuf);
    hipLaunchKernelGGL(conv2_spline, dim3(512),  dim3(512), 0, stream, hbuf, b2, Wt2, x, out);
}

// Round 11
// 77.549 us; speedup vs baseline: 2.1492x; 1.1764x over previous
//
#include <hip/hip_runtime.h>

typedef __attribute__((ext_vector_type(8))) __bf16 bf16x8;
typedef __attribute__((ext_vector_type(4))) float f32x4;

__device__ __forceinline__ unsigned short f2bf(float f) {
    unsigned int u = __builtin_bit_cast(unsigned int, f);
    u = (u + 0x7FFFu + ((u >> 16) & 1u)) >> 16;
    return (unsigned short)u;
}

// ---- K0a: transpose-cast identity half (ch 0..31) to channel-last bf16 ----
__global__ void __launch_bounds__(256) prep_x1(const float* __restrict__ x,
                                               unsigned short* __restrict__ x1b) {
    int bh = blockIdx.x;                  // b*64 + h
    __shared__ unsigned short lds[64][34];
    int t = threadIdx.x;
    int w = t & 63, c4 = t >> 6;
    const float* xp = x + (size_t)(bh >> 6) * 262144 + (size_t)(bh & 63) * 64;
#pragma unroll
    for (int co = 0; co < 8; ++co) {
        int c = co * 4 + c4;
        lds[w][c] = f2bf(xp[(size_t)c * 4096 + w]);
    }
    __syncthreads();
    int wq = t >> 2, c0 = (t & 3) * 8;
    uint4 v;
    unsigned short* pv = reinterpret_cast<unsigned short*>(&v);
#pragma unroll
    for (int j = 0; j < 8; ++j) pv[j] = lds[wq][c0 + j];
    *reinterpret_cast<uint4*>(x1b + ((size_t)bh * 64 + wq) * 32 + c0) = v;
}

// ---- K0b: copy identity half f32 -> out ch 0..31 ; init objective slots ----
__global__ void __launch_bounds__(256) prep_copy(const float* __restrict__ x,
                                                 const float* __restrict__ obj,
                                                 float* __restrict__ out) {
    unsigned tid = blockIdx.x * 256 + threadIdx.x;   // 1,048,576 float4 total
    unsigned b = tid >> 15, r = tid & 32767;
    size_t off = (size_t)b * 65536 + r;
    reinterpret_cast<float4*>(out)[off] = reinterpret_cast<const float4*>(x)[off];
    if (tid < 32) out[8388608 + tid] = obj[tid];
}

// ---- K0c: repack weights. Wt1: [tap][o][i].  Wt2: [kc][tap][96][64] ----
__global__ void __launch_bounds__(256) prep_w(const float* __restrict__ W1,
                                              const float* __restrict__ W2,
                                              unsigned short* __restrict__ Wt1,
                                              unsigned short* __restrict__ Wt2) {
    int tid = blockIdx.x * 256 + threadIdx.x;
    if (tid < 36864) {                       // W1: [128][32][9]
        int tt = tid % 9, rem = tid / 9;
        int i = rem & 31, o = rem >> 5;
        Wt1[(tt * 128 + o) * 32 + i] = f2bf(W1[tid]);
    }
    if (tid < 110592) {                      // W2: [96][128][9] -> [kc][tap][o][i%64]
        int tt = tid % 9, rem = tid / 9;
        int i = rem & 127, o = rem >> 7;
        int kc = i >> 6, ii = i & 63;
        Wt2[(((kc * 9 + tt) * 96 + o) * 64) + ii] = f2bf(W2[tid]);
    }
}

// ---- K1: conv1 (32->128 ch) + bias + ReLU -> h bf16 channel-last ----
__global__ void __launch_bounds__(256) conv1_relu(const unsigned short* __restrict__ x1b,
                                                  const float* __restrict__ b1,
                                                  const unsigned short* __restrict__ Wt1,
                                                  unsigned short* __restrict__ hbuf) {
    const int LW = 40;                          // 32 ch + 8 pad (bank spread)
    __shared__ unsigned short sx[6 * 66 * LW];  // 31,680 B
    int wg = blockIdx.x;
    int b = wg >> 4, h0 = (wg & 15) << 2;       // TH = 4 rows
    int t = threadIdx.x;

    if (t < 48) {                               // zero halo cols 0 and 65
        int row = t >> 3, k = t & 7;
        int col = (k & 1) ? 65 : 0, c0 = (k >> 1) * 8;
        *reinterpret_cast<uint4*>(&sx[(row * 66 + col) * LW + c0]) = uint4{0, 0, 0, 0};
    }
#pragma unroll
    for (int j = 0; j < 6; ++j) {               // stage 6 rows x 64 w x 32 ch
        int idx = j * 256 + t;
        int row = idx >> 8, rem = idx & 255;
        int w = rem >> 2, c0 = (rem & 3) * 8;
        int gh = h0 - 1 + row;
        uint4 v = uint4{0, 0, 0, 0};
        if (gh >= 0 && gh < 64)
            v = *reinterpret_cast<const uint4*>(x1b + (((size_t)b * 64 + gh) * 64 + w) * 32 + c0);
        *reinterpret_cast<uint4*>(&sx[(row * 66 + (w + 1)) * LW + c0]) = v;
    }
    __syncthreads();

    int wid = t >> 6, lane = t & 63;
    int lrow = lane & 15, kgrp = lane >> 4;

    bf16x8 afr[2][9];                           // hoist weights: 2 M-tiles x 9 taps
#pragma unroll
    for (int m2 = 0; m2 < 2; ++m2) {
        int o = (wid * 2 + m2) * 16 + lrow;
#pragma unroll
        for (int tap = 0; tap < 9; ++tap)
            afr[m2][tap] = *reinterpret_cast<const bf16x8*>(
                Wt1 + (size_t)(tap * 128 + o) * 32 + kgrp * 8);
    }

    for (int nt = 0; nt < 16; ++nt) {
        int r = nt >> 2, ww = ((nt & 3) << 4) + lrow;
        f32x4 acc0 = {0.f, 0.f, 0.f, 0.f}, acc1 = {0.f, 0.f, 0.f, 0.f};
#pragma unroll
        for (int dh = 0; dh < 3; ++dh)
#pragma unroll
            for (int dw = 0; dw < 3; ++dw) {
                int tap = dh * 3 + dw;
                bf16x8 bfr = *reinterpret_cast<const bf16x8*>(
                    &sx[((r + dh) * 66 + ww + dw) * LW + kgrp * 8]);
                acc0 = __builtin_amdgcn_mfma_f32_16x16x32_bf16(afr[0][tap], bfr, acc0, 0, 0, 0);
                acc1 = __builtin_amdgcn_mfma_f32_16x16x32_bf16(afr[1][tap], bfr, acc1, 0, 0, 0);
            }
        int hh = h0 + r;
        size_t obase = (((size_t)b * 64 + hh) * 64 + ww) * 128;
#pragma unroll
        for (int m2 = 0; m2 < 2; ++m2) {
            f32x4 a = (m2 == 0) ? acc0 : acc1;
            int o0 = (wid * 2 + m2) * 16 + kgrp * 4;
            unsigned short r4[4];
#pragma unroll
            for (int j = 0; j < 4; ++j) {
                float v = a[j] + b1[o0 + j];
                r4[j] = f2bf(fmaxf(v, 0.f));
            }
            uint2 pk;
            pk.x = (unsigned)r4[0] | ((unsigned)r4[1] << 16);
            pk.y = (unsigned)r4[2] | ((unsigned)r4[3] << 16);
            *reinterpret_cast<uint2*>(hbuf + obase + o0) = pk;
        }
    }
}

// ---- K2 v10: v8's proven kernel (padded LDS, passed @64us) + register
//      ping-pong weight prefetch: issue slice s+1 global loads BEFORE the
//      MFMA phase, ds_write AFTER the reads-done barrier (T14 split).
//      Swizzle reverted (v9's objective-check failure).
__global__ void __launch_bounds__(512) conv2_spline(const unsigned short* __restrict__ hbuf,
                                                    const float* __restrict__ b2,
                                                    const unsigned short* __restrict__ Wt2,
                                                    const float* __restrict__ x,
                                                    float* __restrict__ out) {
    const int LWA = 72;                          // act: 64 ch + 8 pad
    const int LWW = 72;                          // wgt: 64 ch + 8 pad
    __shared__ unsigned short sa[6 * 66 * LWA];  // 57,024 B act (6 rows incl halo)
    __shared__ unsigned short sw[96 * LWW];      // 13,824 B weights [96 out][64 ch]
    __shared__ float red[8];
    float* pm = reinterpret_cast<float*>(sa);    // params alias [128][101] f32 = 51,712 B

    int raw = blockIdx.x;                        // 512 blocks
    int wg = (raw & 7) * 64 + (raw >> 3);        // XCD-contiguous swizzle (bijective)
    int b = wg >> 4, h0 = (wg & 15) << 2;        // TH = 4 rows
    int t = threadIdx.x;
    int wid = t >> 6, lane = t & 63;
    int lrow = lane & 15, kgrp = lane >> 4;
    int mgrp = wid >> 2, ngrp = wid & 3;         // 2 Mgrp x 4 Ngrp
    int mb = mgrp * 3;                           // 3 M-tiles (48 ch) per wave

    // per-thread weight-stage mapping (linear chunks, padded dest)
    int wo_a = t >> 3, wk_a = t & 7;
    int wdst_a = wo_a * LWW + wk_a * 8;
    int wsrc_a = wo_a * 64 + wk_a * 8;
    int f2 = 512 + t;
    int wo_b = f2 >> 3, wk_b = f2 & 7;
    int wdst_b = wo_b * LWW + wk_b * 8;
    int wsrc_b = wo_b * 64 + wk_b * 8;

    f32x4 acc[3][4];
#pragma unroll
    for (int i = 0; i < 3; ++i)
#pragma unroll
        for (int j = 0; j < 4; ++j) acc[i][j] = f32x4{0.f, 0.f, 0.f, 0.f};

    // prologue: stage weight slice 0
    {
        uint4 v1 = *reinterpret_cast<const uint4*>(Wt2 + wsrc_a);
        *reinterpret_cast<uint4*>(&sw[wdst_a]) = v1;
        if (t < 256) {
            uint4 v2 = *reinterpret_cast<const uint4*>(Wt2 + wsrc_b);
            *reinterpret_cast<uint4*>(&sw[wdst_b]) = v2;
        }
    }

    for (int kc2 = 0; kc2 < 2; ++kc2) {          // two 64-channel K chunks
        // stage act: rows h0-1..h0+4, 64 w, 64 ch (3072 uint4).
        // No leading barrier needed: prior tap-loop ended with a barrier.
#pragma unroll
        for (int j = 0; j < 6; ++j) {
            int idx = j * 512 + t;
            int row = idx >> 9, rem = idx & 511;
            int w = rem >> 3, c0 = (rem & 7) * 8;
            int gh = h0 - 1 + row;
            uint4 v = uint4{0, 0, 0, 0};
            if (gh >= 0 && gh < 64)
                v = *reinterpret_cast<const uint4*>(
                    hbuf + (((size_t)b * 64 + gh) * 64 + w) * 128 + kc2 * 64 + c0);
            *reinterpret_cast<uint4*>(&sa[(row * 66 + (w + 1)) * LWA + c0]) = v;
        }
        if (t < 96) {                            // zero halo cols 0 and 65
            int row = t >> 4, k = t & 15;
            int col = (k & 1) ? 65 : 0, c0 = (k >> 1) * 8;
            *reinterpret_cast<uint4*>(&sa[(row * 66 + col) * LWA + c0]) = uint4{0, 0, 0, 0};
        }
        __syncthreads();                         // act + current weight slice visible

        for (int tap = 0; tap < 9; ++tap) {
            int s = kc2 * 9 + tap;
            // issue next-slice weight loads EARLY (L2 latency hides under MFMA)
            uint4 v1, v2;
            if (s < 17) {
                const unsigned short* wsrc = Wt2 + (size_t)(s + 1) * 6144;
                v1 = *reinterpret_cast<const uint4*>(wsrc + wsrc_a);
                if (t < 256) v2 = *reinterpret_cast<const uint4*>(wsrc + wsrc_b);
            }

            int dh = tap / 3, dw = tap % 3;
            bf16x8 wfr[3][2];
#pragma unroll
            for (int mi = 0; mi < 3; ++mi) {
                int o = (mb + mi) * 16 + lrow;
                wfr[mi][0] = *reinterpret_cast<const bf16x8*>(&sw[o * LWW + kgrp * 8]);
                wfr[mi][1] = *reinterpret_cast<const bf16x8*>(&sw[o * LWW + 32 + kgrp * 8]);
            }
#pragma unroll
            for (int ni = 0; ni < 4; ++ni) {
                int nt = ngrp * 4 + ni;
                int rr = nt >> 2, wcol = (nt & 3) * 16 + lrow;
                int base = ((rr + dh) * 66 + wcol + dw) * LWA;
                bf16x8 a0 = *reinterpret_cast<const bf16x8*>(&sa[base + kgrp * 8]);
                bf16x8 a1 = *reinterpret_cast<const bf16x8*>(&sa[base + 32 + kgrp * 8]);
#pragma unroll
                for (int mi = 0; mi < 3; ++mi) {
                    acc[mi][ni] = __builtin_amdgcn_mfma_f32_16x16x32_bf16(wfr[mi][0], a0, acc[mi][ni], 0, 0, 0);
                    acc[mi][ni] = __builtin_amdgcn_mfma_f32_16x16x32_bf16(wfr[mi][1], a1, acc[mi][ni], 0, 0, 0);
                }
            }
            __syncthreads();                     // all reads of sw (and sa this tap) done
            if (s < 17) {                        // write staged weights LATE
                *reinterpret_cast<uint4*>(&sw[wdst_a]) = v1;
                if (t < 256) *reinterpret_cast<uint4*>(&sw[wdst_b]) = v2;
            }
            __syncthreads();                     // new slice visible for next tap
        }
    }

    // ---- epilogue: two 128-position halves (params f32 aliased over sa) ----
    float lad_acc = 0.f;
    for (int half = 0; half < 2; ++half) {
        __syncthreads();                         // acc done / prev-half spline reads done
        if ((ngrp >> 1) == half) {               // ngrp {0,1}->half0, {2,3}->half1
#pragma unroll
            for (int mi = 0; mi < 3; ++mi) {
                int o0 = (mb + mi) * 16 + kgrp * 4;
                float bb0 = b2[o0], bb1 = b2[o0 + 1], bb2 = b2[o0 + 2], bb3 = b2[o0 + 3];
#pragma unroll
                for (int ni = 0; ni < 4; ++ni) {
                    int p = (ngrp & 1) * 64 + ni * 16 + lrow;   // 0..127 within half
                    f32x4 v = acc[mi][ni];
                    pm[p * 101 + o0]     = v[0] + bb0;
                    pm[p * 101 + o0 + 1] = v[1] + bb1;
                    pm[p * 101 + o0 + 2] = v[2] + bb2;
                    pm[p * 101 + o0 + 3] = v[3] + bb3;
                }
            }
        }
        __syncthreads();
        // spline: 128 pos x 32 spline-ch = 4096 elems, 512 thr x 8 iters
#pragma unroll 4
        for (int it = 0; it < 8; ++it) {
            int idx = it * 512 + t;
            int c = idx >> 7, p = idx & 127;
            int pos = half * 128 + p;
            int pb = p * 101 + 3 * c;
            float u0 = pm[pb];
            float u1 = pm[pb + 1];
            float u2 = pm[pb + 2];
            size_t gpos = (size_t)(b * 64 + 32 + c) * 4096 + (size_t)(h0 + (pos >> 6)) * 64 + (pos & 63);
            float xin = x[gpos];
            float mx = fmaxf(u0, fmaxf(u1, u2));
            float e0 = __expf(u0 - mx), e1 = __expf(u1 - mx), e2 = __expf(u2 - mx);
            float s = e0 + e1 + e2;
            float inv = 1.0f / s;
            float pos01 = fminf(fmaxf((xin + 1.f) * 0.5f, 0.f), 1.f) * 3.f;
            int bin = (int)pos01; bin = bin > 2 ? 2 : bin;
            float alpha = pos01 - (float)bin;
            float eb = (bin == 0) ? e0 : ((bin == 1) ? e1 : e2);
            float cb = (bin == 0) ? 0.f : ((bin == 1) ? e0 : (e0 + e1));
            float pk = eb * inv;
            float outv = cb * inv + alpha * pk;
            outv = fminf(fmaxf(outv, 0.f), 1.f) * 2.f - 1.f;
            float lad = __logf(pk) + 1.09861228866810969f;   // + log(3)
            bool inside = (xin >= -1.f) && (xin <= 1.f);
            if (!inside) { outv = xin; lad = 0.f; }
            out[gpos] = outv;
            lad_acc += lad;
        }
    }
#pragma unroll
    for (int off = 32; off > 0; off >>= 1)
        lad_acc += __shfl_down(lad_acc, off, 64);
    if (lane == 0) red[wid] = lad_acc;
    __syncthreads();
    if (t == 0) {
        float s = 0.f;
#pragma unroll
        for (int i = 0; i < 8; ++i) s += red[i];
        atomicAdd(out + 8388608 + b, s);
    }
}

extern "C" void kernel_launch(void* const* d_in, const int* in_sizes, int n_in,
                              void* d_out, int out_size, void* d_ws, size_t ws_size,
                              hipStream_t stream) {
    const float* x   = (const float*)d_in[0];
    const float* obj = (const float*)d_in[1];
    const float* W1  = (const float*)d_in[2];
    const float* b1  = (const float*)d_in[3];
    const float* W2  = (const float*)d_in[4];
    const float* b2  = (const float*)d_in[5];
    float* out = (float*)d_out;
    char* ws = (char*)d_ws;

    unsigned short* x1b  = (unsigned short*)ws;                          //  8,388,608 B
    unsigned short* hbuf = (unsigned short*)(ws + 8388608);              // 33,554,432 B
    unsigned short* Wt1  = (unsigned short*)(ws + 8388608 + 33554432);   //     73,728 B
    unsigned short* Wt2  = (unsigned short*)(ws + 8388608 + 33554432 + 73728); // 221,184 B

    hipLaunchKernelGGL(prep_x1,      dim3(2048), dim3(256), 0, stream, x, x1b);
    hipLaunchKernelGGL(prep_copy,    dim3(4096), dim3(256), 0, stream, x, obj, out);
    hipLaunchKernelGGL(prep_w,       dim3(432),  dim3(256), 0, stream, W1, W2, Wt1, Wt2);
    hipLaunchKernelGGL(conv1_relu,   dim3(512),  dim3(256), 0, stream, x1b, b1, Wt1, hbuf);
    hipLaunchKernelGGL(conv2_spline, dim3(512),  dim3(512), 0, stream, hbuf, b2, Wt2, x, out);
}

// Round 12
// 73.849 us; speedup vs baseline: 2.2568x; 1.0501x over previous
//
#include <hip/hip_runtime.h>

typedef __attribute__((ext_vector_type(8))) __bf16 bf16x8;
typedef __attribute__((ext_vector_type(4))) float f32x4;

__device__ __forceinline__ unsigned short f2bf(float f) {
    unsigned int u = __builtin_bit_cast(unsigned int, f);
    u = (u + 0x7FFFu + ((u >> 16) & 1u)) >> 16;
    return (unsigned short)u;
}

// ---- K0: repack weights. Wt1: [tap][o][i].  Wt2: [kc][tap][96][64] ----
__global__ void __launch_bounds__(256) prep_w(const float* __restrict__ W1,
                                              const float* __restrict__ W2,
                                              unsigned short* __restrict__ Wt1,
                                              unsigned short* __restrict__ Wt2) {
    int tid = blockIdx.x * 256 + threadIdx.x;
    if (tid < 36864) {                       // W1: [128][32][9]
        int tt = tid % 9, rem = tid / 9;
        int i = rem & 31, o = rem >> 5;
        Wt1[(tt * 128 + o) * 32 + i] = f2bf(W1[tid]);
    }
    if (tid < 110592) {                      // W2: [96][128][9] -> [kc][tap][o][i%64]
        int tt = tid % 9, rem = tid / 9;
        int i = rem & 127, o = rem >> 7;
        int kc = i >> 6, ii = i & 63;
        Wt2[(((kc * 9 + tt) * 96 + o) * 64) + ii] = f2bf(W2[tid]);
    }
}

// ---- K1 fused: identity copy + objective init + transpose-stage x (ch 0..31)
//      + conv1 (32->128 ch) + bias + ReLU -> h bf16 channel-last ----
__global__ void __launch_bounds__(256) conv1_fused(const float* __restrict__ x,
                                                   const float* __restrict__ obj,
                                                   const float* __restrict__ b1,
                                                   const unsigned short* __restrict__ Wt1,
                                                   unsigned short* __restrict__ hbuf,
                                                   float* __restrict__ out) {
    const int LW = 40;                          // 32 ch + 8 pad
    __shared__ unsigned short sx[6 * 66 * LW];  // 31,680 B
    int wg = blockIdx.x;
    int b = wg >> 4, h0 = (wg & 15) << 2;       // TH = 4 rows
    int t = threadIdx.x;

    // -- identity half copy (f32 float4) + objective init, independent of LDS --
#pragma unroll
    for (int j = 0; j < 8; ++j) {
        int idx = j * 256 + t;                  // 2048 float4 = 4 rows x 32 ch x 16 w4
        int c = idx >> 6, row = (idx >> 4) & 3, w4 = idx & 15;
        size_t off = (((size_t)b * 64 + c) * 64 + (h0 + row)) * 16 + w4;  // float4 units
        reinterpret_cast<float4*>(out)[off] =
            reinterpret_cast<const float4*>(x)[off];
    }
    if (wg == 0 && t < 32) out[8388608 + t] = obj[t];

    // -- stage + transpose x[b, 0:32, h0-1..h0+4, :] -> sx[row][w+1][c] bf16 --
    if (t < 48) {                               // zero halo cols 0 and 65
        int row = t >> 3, k = t & 7;
        int col = (k & 1) ? 65 : 0, c0 = (k >> 1) * 8;
        *reinterpret_cast<uint4*>(&sx[(row * 66 + col) * LW + c0]) = uint4{0, 0, 0, 0};
    }
    {
        int w = t & 63, c4 = t >> 6;            // wave reads one channel-row (256B)
        const float* xb = x + (size_t)b * 262144;
#pragma unroll
        for (int row = 0; row < 6; ++row) {
            int gh = h0 - 1 + row;
            if (gh >= 0 && gh < 64) {
                const float* xr = xb + (size_t)gh * 64;
#pragma unroll
                for (int co = 0; co < 8; ++co) {
                    int c = co * 4 + c4;
                    sx[(row * 66 + w + 1) * LW + c] = f2bf(xr[(size_t)c * 4096 + w]);
                }
            } else {
#pragma unroll
                for (int co = 0; co < 8; ++co) {
                    int c = co * 4 + c4;
                    sx[(row * 66 + w + 1) * LW + c] = 0;
                }
            }
        }
    }
    __syncthreads();

    int wid = t >> 6, lane = t & 63;
    int lrow = lane & 15, kgrp = lane >> 4;

    bf16x8 afr[2][9];                           // hoist weights: 2 M-tiles x 9 taps
#pragma unroll
    for (int m2 = 0; m2 < 2; ++m2) {
        int o = (wid * 2 + m2) * 16 + lrow;
#pragma unroll
        for (int tap = 0; tap < 9; ++tap)
            afr[m2][tap] = *reinterpret_cast<const bf16x8*>(
                Wt1 + (size_t)(tap * 128 + o) * 32 + kgrp * 8);
    }

    for (int nt = 0; nt < 16; ++nt) {
        int r = nt >> 2, ww = ((nt & 3) << 4) + lrow;
        f32x4 acc0 = {0.f, 0.f, 0.f, 0.f}, acc1 = {0.f, 0.f, 0.f, 0.f};
#pragma unroll
        for (int dh = 0; dh < 3; ++dh)
#pragma unroll
            for (int dw = 0; dw < 3; ++dw) {
                int tap = dh * 3 + dw;
                bf16x8 bfr = *reinterpret_cast<const bf16x8*>(
                    &sx[((r + dh) * 66 + ww + dw) * LW + kgrp * 8]);
                acc0 = __builtin_amdgcn_mfma_f32_16x16x32_bf16(afr[0][tap], bfr, acc0, 0, 0, 0);
                acc1 = __builtin_amdgcn_mfma_f32_16x16x32_bf16(afr[1][tap], bfr, acc1, 0, 0, 0);
            }
        int hh = h0 + r;
        size_t obase = (((size_t)b * 64 + hh) * 64 + ww) * 128;
#pragma unroll
        for (int m2 = 0; m2 < 2; ++m2) {
            f32x4 a = (m2 == 0) ? acc0 : acc1;
            int o0 = (wid * 2 + m2) * 16 + kgrp * 4;
            unsigned short r4[4];
#pragma unroll
            for (int j = 0; j < 4; ++j) {
                float v = a[j] + b1[o0 + j];
                r4[j] = f2bf(fmaxf(v, 0.f));
            }
            uint2 pk;
            pk.x = (unsigned)r4[0] | ((unsigned)r4[1] << 16);
            pk.y = (unsigned)r4[2] | ((unsigned)r4[3] << 16);
            *reinterpret_cast<uint2*>(hbuf + obase + o0) = pk;
        }
    }
}

// ---- K2 v10 (UNCHANGED — control): padded LDS + T14 weight prefetch ----
__global__ void __launch_bounds__(512) conv2_spline(const unsigned short* __restrict__ hbuf,
                                                    const float* __restrict__ b2,
                                                    const unsigned short* __restrict__ Wt2,
                                                    const float* __restrict__ x,
                                                    float* __restrict__ out) {
    const int LWA = 72;                          // act: 64 ch + 8 pad
    const int LWW = 72;                          // wgt: 64 ch + 8 pad
    __shared__ unsigned short sa[6 * 66 * LWA];  // 57,024 B act (6 rows incl halo)
    __shared__ unsigned short sw[96 * LWW];      // 13,824 B weights [96 out][64 ch]
    __shared__ float red[8];
    float* pm = reinterpret_cast<float*>(sa);    // params alias [128][101] f32 = 51,712 B

    int raw = blockIdx.x;                        // 512 blocks
    int wg = (raw & 7) * 64 + (raw >> 3);        // XCD-contiguous swizzle (bijective)
    int b = wg >> 4, h0 = (wg & 15) << 2;        // TH = 4 rows
    int t = threadIdx.x;
    int wid = t >> 6, lane = t & 63;
    int lrow = lane & 15, kgrp = lane >> 4;
    int mgrp = wid >> 2, ngrp = wid & 3;         // 2 Mgrp x 4 Ngrp
    int mb = mgrp * 3;                           // 3 M-tiles (48 ch) per wave

    // per-thread weight-stage mapping (linear chunks, padded dest)
    int wo_a = t >> 3, wk_a = t & 7;
    int wdst_a = wo_a * LWW + wk_a * 8;
    int wsrc_a = wo_a * 64 + wk_a * 8;
    int f2 = 512 + t;
    int wo_b = f2 >> 3, wk_b = f2 & 7;
    int wdst_b = wo_b * LWW + wk_b * 8;
    int wsrc_b = wo_b * 64 + wk_b * 8;

    f32x4 acc[3][4];
#pragma unroll
    for (int i = 0; i < 3; ++i)
#pragma unroll
        for (int j = 0; j < 4; ++j) acc[i][j] = f32x4{0.f, 0.f, 0.f, 0.f};

    // prologue: stage weight slice 0
    {
        uint4 v1 = *reinterpret_cast<const uint4*>(Wt2 + wsrc_a);
        *reinterpret_cast<uint4*>(&sw[wdst_a]) = v1;
        if (t < 256) {
            uint4 v2 = *reinterpret_cast<const uint4*>(Wt2 + wsrc_b);
            *reinterpret_cast<uint4*>(&sw[wdst_b]) = v2;
        }
    }

    for (int kc2 = 0; kc2 < 2; ++kc2) {          // two 64-channel K chunks
#pragma unroll
        for (int j = 0; j < 6; ++j) {
            int idx = j * 512 + t;
            int row = idx >> 9, rem = idx & 511;
            int w = rem >> 3, c0 = (rem & 7) * 8;
            int gh = h0 - 1 + row;
            uint4 v = uint4{0, 0, 0, 0};
            if (gh >= 0 && gh < 64)
                v = *reinterpret_cast<const uint4*>(
                    hbuf + (((size_t)b * 64 + gh) * 64 + w) * 128 + kc2 * 64 + c0);
            *reinterpret_cast<uint4*>(&sa[(row * 66 + (w + 1)) * LWA + c0]) = v;
        }
        if (t < 96) {                            // zero halo cols 0 and 65
            int row = t >> 4, k = t & 15;
            int col = (k & 1) ? 65 : 0, c0 = (k >> 1) * 8;
            *reinterpret_cast<uint4*>(&sa[(row * 66 + col) * LWA + c0]) = uint4{0, 0, 0, 0};
        }
        __syncthreads();                         // act + current weight slice visible

        for (int tap = 0; tap < 9; ++tap) {
            int s = kc2 * 9 + tap;
            // issue next-slice weight loads EARLY (L2 latency hides under MFMA)
            uint4 v1, v2;
            if (s < 17) {
                const unsigned short* wsrc = Wt2 + (size_t)(s + 1) * 6144;
                v1 = *reinterpret_cast<const uint4*>(wsrc + wsrc_a);
                if (t < 256) v2 = *reinterpret_cast<const uint4*>(wsrc + wsrc_b);
            }

            int dh = tap / 3, dw = tap % 3;
            bf16x8 wfr[3][2];
#pragma unroll
            for (int mi = 0; mi < 3; ++mi) {
                int o = (mb + mi) * 16 + lrow;
                wfr[mi][0] = *reinterpret_cast<const bf16x8*>(&sw[o * LWW + kgrp * 8]);
                wfr[mi][1] = *reinterpret_cast<const bf16x8*>(&sw[o * LWW + 32 + kgrp * 8]);
            }
#pragma unroll
            for (int ni = 0; ni < 4; ++ni) {
                int nt = ngrp * 4 + ni;
                int rr = nt >> 2, wcol = (nt & 3) * 16 + lrow;
                int base = ((rr + dh) * 66 + wcol + dw) * LWA;
                bf16x8 a0 = *reinterpret_cast<const bf16x8*>(&sa[base + kgrp * 8]);
                bf16x8 a1 = *reinterpret_cast<const bf16x8*>(&sa[base + 32 + kgrp * 8]);
#pragma unroll
                for (int mi = 0; mi < 3; ++mi) {
                    acc[mi][ni] = __builtin_amdgcn_mfma_f32_16x16x32_bf16(wfr[mi][0], a0, acc[mi][ni], 0, 0, 0);
                    acc[mi][ni] = __builtin_amdgcn_mfma_f32_16x16x32_bf16(wfr[mi][1], a1, acc[mi][ni], 0, 0, 0);
                }
            }
            __syncthreads();                     // all reads of sw (and sa this tap) done
            if (s < 17) {                        // write staged weights LATE
                *reinterpret_cast<uint4*>(&sw[wdst_a]) = v1;
                if (t < 256) *reinterpret_cast<uint4*>(&sw[wdst_b]) = v2;
            }
            __syncthreads();                     // new slice visible for next tap
        }
    }

    // ---- epilogue: two 128-position halves (params f32 aliased over sa) ----
    float lad_acc = 0.f;
    for (int half = 0; half < 2; ++half) {
        __syncthreads();                         // acc done / prev-half spline reads done
        if ((ngrp >> 1) == half) {               // ngrp {0,1}->half0, {2,3}->half1
#pragma unroll
            for (int mi = 0; mi < 3; ++mi) {
                int o0 = (mb + mi) * 16 + kgrp * 4;
                float bb0 = b2[o0], bb1 = b2[o0 + 1], bb2 = b2[o0 + 2], bb3 = b2[o0 + 3];
#pragma unroll
                for (int ni = 0; ni < 4; ++ni) {
                    int p = (ngrp & 1) * 64 + ni * 16 + lrow;   // 0..127 within half
                    f32x4 v = acc[mi][ni];
                    pm[p * 101 + o0]     = v[0] + bb0;
                    pm[p * 101 + o0 + 1] = v[1] + bb1;
                    pm[p * 101 + o0 + 2] = v[2] + bb2;
                    pm[p * 101 + o0 + 3] = v[3] + bb3;
                }
            }
        }
        __syncthreads();
        // spline: 128 pos x 32 spline-ch = 4096 elems, 512 thr x 8 iters
#pragma unroll 4
        for (int it = 0; it < 8; ++it) {
            int idx = it * 512 + t;
            int c = idx >> 7, p = idx & 127;
            int pos = half * 128 + p;
            int pb = p * 101 + 3 * c;
            float u0 = pm[pb];
            float u1 = pm[pb + 1];
            float u2 = pm[pb + 2];
            size_t gpos = (size_t)(b * 64 + 32 + c) * 4096 + (size_t)(h0 + (pos >> 6)) * 64 + (pos & 63);
            float xin = x[gpos];
            float mx = fmaxf(u0, fmaxf(u1, u2));
            float e0 = __expf(u0 - mx), e1 = __expf(u1 - mx), e2 = __expf(u2 - mx);
            float s = e0 + e1 + e2;
            float inv = 1.0f / s;
            float pos01 = fminf(fmaxf((xin + 1.f) * 0.5f, 0.f), 1.f) * 3.f;
            int bin = (int)pos01; bin = bin > 2 ? 2 : bin;
            float alpha = pos01 - (float)bin;
            float eb = (bin == 0) ? e0 : ((bin == 1) ? e1 : e2);
            float cb = (bin == 0) ? 0.f : ((bin == 1) ? e0 : (e0 + e1));
            float pk = eb * inv;
            float outv = cb * inv + alpha * pk;
            outv = fminf(fmaxf(outv, 0.f), 1.f) * 2.f - 1.f;
            float lad = __logf(pk) + 1.09861228866810969f;   // + log(3)
            bool inside = (xin >= -1.f) && (xin <= 1.f);
            if (!inside) { outv = xin; lad = 0.f; }
            out[gpos] = outv;
            lad_acc += lad;
        }
    }
#pragma unroll
    for (int off = 32; off > 0; off >>= 1)
        lad_acc += __shfl_down(lad_acc, off, 64);
    if (lane == 0) red[wid] = lad_acc;
    __syncthreads();
    if (t == 0) {
        float s = 0.f;
#pragma unroll
        for (int i = 0; i < 8; ++i) s += red[i];
        atomicAdd(out + 8388608 + b, s);
    }
}

extern "C" void kernel_launch(void* const* d_in, const int* in_sizes, int n_in,
                              void* d_out, int out_size, void* d_ws, size_t ws_size,
                              hipStream_t stream) {
    const float* x   = (const float*)d_in[0];
    const float* obj = (const float*)d_in[1];
    const float* W1  = (const float*)d_in[2];
    const float* b1  = (const float*)d_in[3];
    const float* W2  = (const float*)d_in[4];
    const float* b2  = (const float*)d_in[5];
    float* out = (float*)d_out;
    char* ws = (char*)d_ws;

    unsigned short* hbuf = (unsigned short*)ws;                  // 33,554,432 B
    unsigned short* Wt1  = (unsigned short*)(ws + 33554432);     //     73,728 B
    unsigned short* Wt2  = (unsigned short*)(ws + 33554432 + 73728); // 221,184 B

    hipLaunchKernelGGL(prep_w,       dim3(432), dim3(256), 0, stream, W1, W2, Wt1, Wt2);
    hipLaunchKernelGGL(conv1_fused,  dim3(512), dim3(256), 0, stream, x, obj, b1, Wt1, hbuf, out);
    hipLaunchKernelGGL(conv2_spline, dim3(512), dim3(512), 0, stream, hbuf, b2, Wt2, x, out);
}

// Round 13
// 71.494 us; speedup vs baseline: 2.3312x; 1.0329x over previous
//
#include <hip/hip_runtime.h>

typedef __attribute__((ext_vector_type(8))) __bf16 bf16x8;
typedef __attribute__((ext_vector_type(4))) float f32x4;

__device__ __forceinline__ unsigned short f2bf(float f) {
    unsigned int u = __builtin_bit_cast(unsigned int, f);
    u = (u + 0x7FFFu + ((u >> 16) & 1u)) >> 16;
    return (unsigned short)u;
}

// ---- K0: repack weights. Wt1: [tap][o][i].
//      Wt2: fragment-major per slice s=kc*9+tap:
//      elem = s*6144 + ((o_tile*2 + khalf)*64 + kgrp*16 + lrow)*8 + j ----
__global__ void __launch_bounds__(256) prep_w(const float* __restrict__ W1,
                                              const float* __restrict__ W2,
                                              unsigned short* __restrict__ Wt1,
                                              unsigned short* __restrict__ Wt2) {
    int tid = blockIdx.x * 256 + threadIdx.x;
    if (tid < 36864) {                       // W1: [128][32][9]
        int tt = tid % 9, rem = tid / 9;
        int i = rem & 31, o = rem >> 5;
        Wt1[(tt * 128 + o) * 32 + i] = f2bf(W1[tid]);
    }
    if (tid < 110592) {                      // W2: [96][128][9] -> fragment-major
        int tt = tid % 9, rem = tid / 9;
        int i = rem & 127, o = rem >> 7;
        int kc = i >> 6, ii = i & 63;
        int khalf = ii >> 5, kgrp = (ii >> 3) & 3, j = ii & 7;
        int o_tile = o >> 4, lrow = o & 15;
        int s = kc * 9 + tt;
        Wt2[(size_t)s * 6144 +
            (size_t)(((o_tile * 2 + khalf) * 64 + kgrp * 16 + lrow) * 8 + j)] = f2bf(W2[tid]);
    }
}

// ---- K1 fused: identity copy + objective init + transpose-stage x (ch 0..31)
//      + conv1 (32->128 ch) + bias + ReLU -> h bf16 channel-last ----
__global__ void __launch_bounds__(256) conv1_fused(const float* __restrict__ x,
                                                   const float* __restrict__ obj,
                                                   const float* __restrict__ b1,
                                                   const unsigned short* __restrict__ Wt1,
                                                   unsigned short* __restrict__ hbuf,
                                                   float* __restrict__ out) {
    const int LW = 40;                          // 32 ch + 8 pad
    __shared__ unsigned short sx[6 * 66 * LW];  // 31,680 B
    int wg = blockIdx.x;
    int b = wg >> 4, h0 = (wg & 15) << 2;       // TH = 4 rows
    int t = threadIdx.x;

    // -- identity half copy (f32 float4) + objective init --
#pragma unroll
    for (int j = 0; j < 8; ++j) {
        int idx = j * 256 + t;                  // 2048 float4 = 4 rows x 32 ch x 16 w4
        int c = idx >> 6, row = (idx >> 4) & 3, w4 = idx & 15;
        size_t off = (((size_t)b * 64 + c) * 64 + (h0 + row)) * 16 + w4;  // float4 units
        reinterpret_cast<float4*>(out)[off] =
            reinterpret_cast<const float4*>(x)[off];
    }
    if (wg == 0 && t < 32) out[8388608 + t] = obj[t];

    // -- stage + transpose x[b, 0:32, h0-1..h0+4, :] -> sx[row][w+1][c] bf16 --
    if (t < 48) {                               // zero halo cols 0 and 65
        int row = t >> 3, k = t & 7;
        int col = (k & 1) ? 65 : 0, c0 = (k >> 1) * 8;
        *reinterpret_cast<uint4*>(&sx[(row * 66 + col) * LW + c0]) = uint4{0, 0, 0, 0};
    }
    {
        int w = t & 63, c4 = t >> 6;            // wave reads one channel-row (256B)
        const float* xb = x + (size_t)b * 262144;
#pragma unroll
        for (int row = 0; row < 6; ++row) {
            int gh = h0 - 1 + row;
            if (gh >= 0 && gh < 64) {
                const float* xr = xb + (size_t)gh * 64;
#pragma unroll
                for (int co = 0; co < 8; ++co) {
                    int c = co * 4 + c4;
                    sx[(row * 66 + w + 1) * LW + c] = f2bf(xr[(size_t)c * 4096 + w]);
                }
            } else {
#pragma unroll
                for (int co = 0; co < 8; ++co) {
                    int c = co * 4 + c4;
                    sx[(row * 66 + w + 1) * LW + c] = 0;
                }
            }
        }
    }
    __syncthreads();

    int wid = t >> 6, lane = t & 63;
    int lrow = lane & 15, kgrp = lane >> 4;

    bf16x8 afr[2][9];                           // hoist weights: 2 M-tiles x 9 taps
#pragma unroll
    for (int m2 = 0; m2 < 2; ++m2) {
        int o = (wid * 2 + m2) * 16 + lrow;
#pragma unroll
        for (int tap = 0; tap < 9; ++tap)
            afr[m2][tap] = *reinterpret_cast<const bf16x8*>(
                Wt1 + (size_t)(tap * 128 + o) * 32 + kgrp * 8);
    }

    for (int nt = 0; nt < 16; ++nt) {
        int r = nt >> 2, ww = ((nt & 3) << 4) + lrow;
        f32x4 acc0 = {0.f, 0.f, 0.f, 0.f}, acc1 = {0.f, 0.f, 0.f, 0.f};
#pragma unroll
        for (int dh = 0; dh < 3; ++dh)
#pragma unroll
            for (int dw = 0; dw < 3; ++dw) {
                int tap = dh * 3 + dw;
                bf16x8 bfr = *reinterpret_cast<const bf16x8*>(
                    &sx[((r + dh) * 66 + ww + dw) * LW + kgrp * 8]);
                acc0 = __builtin_amdgcn_mfma_f32_16x16x32_bf16(afr[0][tap], bfr, acc0, 0, 0, 0);
                acc1 = __builtin_amdgcn_mfma_f32_16x16x32_bf16(afr[1][tap], bfr, acc1, 0, 0, 0);
            }
        int hh = h0 + r;
        size_t obase = (((size_t)b * 64 + hh) * 64 + ww) * 128;
#pragma unroll
        for (int m2 = 0; m2 < 2; ++m2) {
            f32x4 a = (m2 == 0) ? acc0 : acc1;
            int o0 = (wid * 2 + m2) * 16 + kgrp * 4;
            unsigned short r4[4];
#pragma unroll
            for (int j = 0; j < 4; ++j) {
                float v = a[j] + b1[o0 + j];
                r4[j] = f2bf(fmaxf(v, 0.f));
            }
            uint2 pk;
            pk.x = (unsigned)r4[0] | ((unsigned)r4[1] << 16);
            pk.y = (unsigned)r4[2] | ((unsigned)r4[3] << 16);
            *reinterpret_cast<uint2*>(hbuf + obase + o0) = pk;
        }
    }
}

// ---- K2 v12: fragment-major weight LDS (conflict-free reads/writes by
//      construction) + ping-pong double-buffer -> ONE barrier per tap.
//      Act layout unchanged from v10 (proven). LDS 81,632 B -> 2 blocks/CU.
__global__ void __launch_bounds__(512) conv2_spline(const unsigned short* __restrict__ hbuf,
                                                    const float* __restrict__ b2,
                                                    const unsigned short* __restrict__ Wt2,
                                                    const float* __restrict__ x,
                                                    float* __restrict__ out) {
    const int LWA = 72;                          // act: 64 ch + 8 pad
    __shared__ __align__(16) unsigned short sa[6 * 66 * LWA];  // 57,024 B
    __shared__ __align__(16) unsigned short swd[2 * 6144];     // 24,576 B ping-pong
    __shared__ float red[8];
    float* pm = reinterpret_cast<float*>(sa);    // params alias [128][101] f32 = 51,712 B

    int raw = blockIdx.x;                        // 512 blocks
    int wg = (raw & 7) * 64 + (raw >> 3);        // XCD-contiguous swizzle (bijective)
    int b = wg >> 4, h0 = (wg & 15) << 2;        // TH = 4 rows
    int t = threadIdx.x;
    int wid = t >> 6, lane = t & 63;
    int lrow = lane & 15, kgrp = lane >> 4;
    int mgrp = wid >> 2, ngrp = wid & 3;         // 2 Mgrp x 4 Ngrp
    int mb = mgrp * 3;                           // 3 M-tiles (48 ch) per wave

    f32x4 acc[3][4];
#pragma unroll
    for (int i = 0; i < 3; ++i)
#pragma unroll
        for (int j = 0; j < 4; ++j) acc[i][j] = f32x4{0.f, 0.f, 0.f, 0.f};

    // prologue: stage weight slice 0 into buffer 0 (thread-linear, conflict-free)
    {
        *reinterpret_cast<uint4*>(&swd[t * 8]) =
            *reinterpret_cast<const uint4*>(Wt2 + t * 8);
        if (t < 256)
            *reinterpret_cast<uint4*>(&swd[(512 + t) * 8]) =
                *reinterpret_cast<const uint4*>(Wt2 + (512 + t) * 8);
    }

    for (int kc2 = 0; kc2 < 2; ++kc2) {          // two 64-channel K chunks
        // stage act (prior tap-loop ended with a barrier; kc2=0 has no prior readers)
#pragma unroll
        for (int j = 0; j < 6; ++j) {
            int idx = j * 512 + t;
            int row = idx >> 9, rem = idx & 511;
            int w = rem >> 3, c0 = (rem & 7) * 8;
            int gh = h0 - 1 + row;
            uint4 v = uint4{0, 0, 0, 0};
            if (gh >= 0 && gh < 64)
                v = *reinterpret_cast<const uint4*>(
                    hbuf + (((size_t)b * 64 + gh) * 64 + w) * 128 + kc2 * 64 + c0);
            *reinterpret_cast<uint4*>(&sa[(row * 66 + (w + 1)) * LWA + c0]) = v;
        }
        if (t < 96) {                            // zero halo cols 0 and 65
            int row = t >> 4, k = t & 15;
            int col = (k & 1) ? 65 : 0, c0 = (k >> 1) * 8;
            *reinterpret_cast<uint4*>(&sa[(row * 66 + col) * LWA + c0]) = uint4{0, 0, 0, 0};
        }
        __syncthreads();                         // act + current weight slice visible

        for (int tap = 0; tap < 9; ++tap) {
            int s = kc2 * 9 + tap;
            unsigned short* swc = swd + (s & 1) * 6144;
            unsigned short* swn = swd + ((s + 1) & 1) * 6144;
            // issue next-slice weight loads EARLY (L2 latency hides under MFMA)
            uint4 v1, v2;
            if (s < 17) {
                const unsigned short* wsrc = Wt2 + (size_t)(s + 1) * 6144;
                v1 = *reinterpret_cast<const uint4*>(wsrc + t * 8);
                if (t < 256) v2 = *reinterpret_cast<const uint4*>(wsrc + (512 + t) * 8);
            }

            int dh = tap / 3, dw = tap % 3;
            // fragment-major: wave reads 64 consecutive 16B chunks (1KB) per frag
            bf16x8 wfr[3][2];
#pragma unroll
            for (int mi = 0; mi < 3; ++mi) {
                int ot = mb + mi;
                wfr[mi][0] = *reinterpret_cast<const bf16x8*>(
                    &swc[((ot * 2 + 0) * 64 + lane) * 8]);
                wfr[mi][1] = *reinterpret_cast<const bf16x8*>(
                    &swc[((ot * 2 + 1) * 64 + lane) * 8]);
            }
#pragma unroll
            for (int ni = 0; ni < 4; ++ni) {
                int nt = ngrp * 4 + ni;
                int rr = nt >> 2, wcol = (nt & 3) * 16 + lrow;
                int base = ((rr + dh) * 66 + wcol + dw) * LWA;
                bf16x8 a0 = *reinterpret_cast<const bf16x8*>(&sa[base + kgrp * 8]);
                bf16x8 a1 = *reinterpret_cast<const bf16x8*>(&sa[base + 32 + kgrp * 8]);
#pragma unroll
                for (int mi = 0; mi < 3; ++mi) {
                    acc[mi][ni] = __builtin_amdgcn_mfma_f32_16x16x32_bf16(wfr[mi][0], a0, acc[mi][ni], 0, 0, 0);
                    acc[mi][ni] = __builtin_amdgcn_mfma_f32_16x16x32_bf16(wfr[mi][1], a1, acc[mi][ni], 0, 0, 0);
                }
            }
            // write next slice into the OTHER buffer (no pre-write barrier needed)
            if (s < 17) {
                *reinterpret_cast<uint4*>(&swn[t * 8]) = v1;
                if (t < 256) *reinterpret_cast<uint4*>(&swn[(512 + t) * 8]) = v2;
            }
            __syncthreads();                     // swn visible; all swc/sa reads done
        }
    }

    // ---- epilogue: two 128-position halves (params f32 aliased over sa) ----
    float lad_acc = 0.f;
    for (int half = 0; half < 2; ++half) {
        __syncthreads();                         // acc done / prev-half spline reads done
        if ((ngrp >> 1) == half) {               // ngrp {0,1}->half0, {2,3}->half1
#pragma unroll
            for (int mi = 0; mi < 3; ++mi) {
                int o0 = (mb + mi) * 16 + kgrp * 4;
                float bb0 = b2[o0], bb1 = b2[o0 + 1], bb2 = b2[o0 + 2], bb3 = b2[o0 + 3];
#pragma unroll
                for (int ni = 0; ni < 4; ++ni) {
                    int p = (ngrp & 1) * 64 + ni * 16 + lrow;   // 0..127 within half
                    f32x4 v = acc[mi][ni];
                    pm[p * 101 + o0]     = v[0] + bb0;
                    pm[p * 101 + o0 + 1] = v[1] + bb1;
                    pm[p * 101 + o0 + 2] = v[2] + bb2;
                    pm[p * 101 + o0 + 3] = v[3] + bb3;
                }
            }
        }
        __syncthreads();
        // spline: 128 pos x 32 spline-ch = 4096 elems, 512 thr x 8 iters
#pragma unroll 4
        for (int it = 0; it < 8; ++it) {
            int idx = it * 512 + t;
            int c = idx >> 7, p = idx & 127;
            int pos = half * 128 + p;
            int pb = p * 101 + 3 * c;
            float u0 = pm[pb];
            float u1 = pm[pb + 1];
            float u2 = pm[pb + 2];
            size_t gpos = (size_t)(b * 64 + 32 + c) * 4096 + (size_t)(h0 + (pos >> 6)) * 64 + (pos & 63);
            float xin = x[gpos];
            float mx = fmaxf(u0, fmaxf(u1, u2));
            float e0 = __expf(u0 - mx), e1 = __expf(u1 - mx), e2 = __expf(u2 - mx);
            float s = e0 + e1 + e2;
            float inv = 1.0f / s;
            float pos01 = fminf(fmaxf((xin + 1.f) * 0.5f, 0.f), 1.f) * 3.f;
            int bin = (int)pos01; bin = bin > 2 ? 2 : bin;
            float alpha = pos01 - (float)bin;
            float eb = (bin == 0) ? e0 : ((bin == 1) ? e1 : e2);
            float cb = (bin == 0) ? 0.f : ((bin == 1) ? e0 : (e0 + e1));
            float pk = eb * inv;
            float outv = cb * inv + alpha * pk;
            outv = fminf(fmaxf(outv, 0.f), 1.f) * 2.f - 1.f;
            float lad = __logf(pk) + 1.09861228866810969f;   // + log(3)
            bool inside = (xin >= -1.f) && (xin <= 1.f);
            if (!inside) { outv = xin; lad = 0.f; }
            out[gpos] = outv;
            lad_acc += lad;
        }
    }
#pragma unroll
    for (int off = 32; off > 0; off >>= 1)
        lad_acc += __shfl_down(lad_acc, off, 64);
    if (lane == 0) red[wid] = lad_acc;
    __syncthreads();
    if (t == 0) {
        float s = 0.f;
#pragma unroll
        for (int i = 0; i < 8; ++i) s += red[i];
        atomicAdd(out + 8388608 + b, s);
    }
}

extern "C" void kernel_launch(void* const* d_in, const int* in_sizes, int n_in,
                              void* d_out, int out_size, void* d_ws, size_t ws_size,
                              hipStream_t stream) {
    const float* x   = (const float*)d_in[0];
    const float* obj = (const float*)d_in[1];
    const float* W1  = (const float*)d_in[2];
    const float* b1  = (const float*)d_in[3];
    const float* W2  = (const float*)d_in[4];
    const float* b2  = (const float*)d_in[5];
    float* out = (float*)d_out;
    char* ws = (char*)d_ws;

    unsigned short* hbuf = (unsigned short*)ws;                  // 33,554,432 B
    unsigned short* Wt1  = (unsigned short*)(ws + 33554432);     //     73,728 B
    unsigned short* Wt2  = (unsigned short*)(ws + 33554432 + 73728); // 221,184 B

    hipLaunchKernelGGL(prep_w,       dim3(432), dim3(256), 0, stream, W1, W2, Wt1, Wt2);
    hipLaunchKernelGGL(conv1_fused,  dim3(512), dim3(256), 0, stream, x, obj, b1, Wt1, hbuf, out);
    hipLaunchKernelGGL(conv2_spline, dim3(512), dim3(512), 0, stream, hbuf, b2, Wt2, x, out);
}

// Round 14
// 71.020 us; speedup vs baseline: 2.3467x; 1.0067x over previous
//
#include <hip/hip_runtime.h>

typedef __attribute__((ext_vector_type(8))) __bf16 bf16x8;
typedef __attribute__((ext_vector_type(4))) float f32x4;

__device__ __forceinline__ unsigned short f2bf(float f) {
    unsigned int u = __builtin_bit_cast(unsigned int, f);
    u = (u + 0x7FFFu + ((u >> 16) & 1u)) >> 16;
    return (unsigned short)u;
}

// ---- K0: repack weights. Wt1: [tap][o][i].
//      Wt2: fragment-major per slice s=kc*9+tap:
//      elem = s*6144 + ((o_tile*2 + khalf)*64 + kgrp*16 + lrow)*8 + j ----
__global__ void __launch_bounds__(256) prep_w(const float* __restrict__ W1,
                                              const float* __restrict__ W2,
                                              unsigned short* __restrict__ Wt1,
                                              unsigned short* __restrict__ Wt2) {
    int tid = blockIdx.x * 256 + threadIdx.x;
    if (tid < 36864) {                       // W1: [128][32][9]
        int tt = tid % 9, rem = tid / 9;
        int i = rem & 31, o = rem >> 5;
        Wt1[(tt * 128 + o) * 32 + i] = f2bf(W1[tid]);
    }
    if (tid < 110592) {                      // W2: [96][128][9] -> fragment-major
        int tt = tid % 9, rem = tid / 9;
        int i = rem & 127, o = rem >> 7;
        int kc = i >> 6, ii = i & 63;
        int khalf = ii >> 5, kgrp = (ii >> 3) & 3, j = ii & 7;
        int o_tile = o >> 4, lrow = o & 15;
        int s = kc * 9 + tt;
        Wt2[(size_t)s * 6144 +
            (size_t)(((o_tile * 2 + khalf) * 64 + kgrp * 16 + lrow) * 8 + j)] = f2bf(W2[tid]);
    }
}

// ---- K1 fused: identity copy + objective init + transpose-stage x (ch 0..31)
//      + conv1 (32->128 ch) + bias + ReLU -> h bf16 channel-last ----
__global__ void __launch_bounds__(256) conv1_fused(const float* __restrict__ x,
                                                   const float* __restrict__ obj,
                                                   const float* __restrict__ b1,
                                                   const unsigned short* __restrict__ Wt1,
                                                   unsigned short* __restrict__ hbuf,
                                                   float* __restrict__ out) {
    const int LW = 40;                          // 32 ch + 8 pad
    __shared__ unsigned short sx[6 * 66 * LW];  // 31,680 B
    int wg = blockIdx.x;
    int b = wg >> 4, h0 = (wg & 15) << 2;       // TH = 4 rows
    int t = threadIdx.x;

    // -- identity half copy (f32 float4) + objective init --
#pragma unroll
    for (int j = 0; j < 8; ++j) {
        int idx = j * 256 + t;                  // 2048 float4 = 4 rows x 32 ch x 16 w4
        int c = idx >> 6, row = (idx >> 4) & 3, w4 = idx & 15;
        size_t off = (((size_t)b * 64 + c) * 64 + (h0 + row)) * 16 + w4;  // float4 units
        reinterpret_cast<float4*>(out)[off] =
            reinterpret_cast<const float4*>(x)[off];
    }
    if (wg == 0 && t < 32) out[8388608 + t] = obj[t];

    // -- stage + transpose x[b, 0:32, h0-1..h0+4, :] -> sx[row][w+1][c] bf16 --
    if (t < 48) {                               // zero halo cols 0 and 65
        int row = t >> 3, k = t & 7;
        int col = (k & 1) ? 65 : 0, c0 = (k >> 1) * 8;
        *reinterpret_cast<uint4*>(&sx[(row * 66 + col) * LW + c0]) = uint4{0, 0, 0, 0};
    }
    {
        int w = t & 63, c4 = t >> 6;            // wave reads one channel-row (256B)
        const float* xb = x + (size_t)b * 262144;
#pragma unroll
        for (int row = 0; row < 6; ++row) {
            int gh = h0 - 1 + row;
            if (gh >= 0 && gh < 64) {
                const float* xr = xb + (size_t)gh * 64;
#pragma unroll
                for (int co = 0; co < 8; ++co) {
                    int c = co * 4 + c4;
                    sx[(row * 66 + w + 1) * LW + c] = f2bf(xr[(size_t)c * 4096 + w]);
                }
            } else {
#pragma unroll
                for (int co = 0; co < 8; ++co) {
                    int c = co * 4 + c4;
                    sx[(row * 66 + w + 1) * LW + c] = 0;
                }
            }
        }
    }
    __syncthreads();

    int wid = t >> 6, lane = t & 63;
    int lrow = lane & 15, kgrp = lane >> 4;

    bf16x8 afr[2][9];                           // hoist weights: 2 M-tiles x 9 taps
#pragma unroll
    for (int m2 = 0; m2 < 2; ++m2) {
        int o = (wid * 2 + m2) * 16 + lrow;
#pragma unroll
        for (int tap = 0; tap < 9; ++tap)
            afr[m2][tap] = *reinterpret_cast<const bf16x8*>(
                Wt1 + (size_t)(tap * 128 + o) * 32 + kgrp * 8);
    }

    for (int nt = 0; nt < 16; ++nt) {
        int r = nt >> 2, ww = ((nt & 3) << 4) + lrow;
        f32x4 acc0 = {0.f, 0.f, 0.f, 0.f}, acc1 = {0.f, 0.f, 0.f, 0.f};
#pragma unroll
        for (int dh = 0; dh < 3; ++dh)
#pragma unroll
            for (int dw = 0; dw < 3; ++dw) {
                int tap = dh * 3 + dw;
                bf16x8 bfr = *reinterpret_cast<const bf16x8*>(
                    &sx[((r + dh) * 66 + ww + dw) * LW + kgrp * 8]);
                acc0 = __builtin_amdgcn_mfma_f32_16x16x32_bf16(afr[0][tap], bfr, acc0, 0, 0, 0);
                acc1 = __builtin_amdgcn_mfma_f32_16x16x32_bf16(afr[1][tap], bfr, acc1, 0, 0, 0);
            }
        int hh = h0 + r;
        size_t obase = (((size_t)b * 64 + hh) * 64 + ww) * 128;
#pragma unroll
        for (int m2 = 0; m2 < 2; ++m2) {
            f32x4 a = (m2 == 0) ? acc0 : acc1;
            int o0 = (wid * 2 + m2) * 16 + kgrp * 4;
            unsigned short r4[4];
#pragma unroll
            for (int j = 0; j < 4; ++j) {
                float v = a[j] + b1[o0 + j];
                r4[j] = f2bf(fmaxf(v, 0.f));
            }
            uint2 pk;
            pk.x = (unsigned)r4[0] | ((unsigned)r4[1] << 16);
            pk.y = (unsigned)r4[2] | ((unsigned)r4[3] << 16);
            *reinterpret_cast<uint2*>(hbuf + obase + o0) = pk;
        }
    }
}

// ---- K2 v13: weights read DIRECTLY from L2 (fragment-major, 1KB coalesced
//      bursts, L2-broadcast across blocks) -> no weight LDS, no in-tap
//      barriers. Tap loop is barrier-free per kc chunk; compiler pipelines.
//      LDS = act 57KB only. Act layout + epilogue unchanged (proven).
__global__ void __launch_bounds__(512) conv2_spline(const unsigned short* __restrict__ hbuf,
                                                    const float* __restrict__ b2,
                                                    const unsigned short* __restrict__ Wt2,
                                                    const float* __restrict__ x,
                                                    float* __restrict__ out) {
    const int LWA = 72;                          // act: 64 ch + 8 pad
    __shared__ __align__(16) unsigned short sa[6 * 66 * LWA];  // 57,024 B
    __shared__ float red[8];
    float* pm = reinterpret_cast<float*>(sa);    // params alias [128][101] f32 = 51,712 B

    int raw = blockIdx.x;                        // 512 blocks
    int wg = (raw & 7) * 64 + (raw >> 3);        // XCD-contiguous swizzle (bijective)
    int b = wg >> 4, h0 = (wg & 15) << 2;        // TH = 4 rows
    int t = threadIdx.x;
    int wid = t >> 6, lane = t & 63;
    int lrow = lane & 15, kgrp = lane >> 4;
    int mgrp = wid >> 2, ngrp = wid & 3;         // 2 Mgrp x 4 Ngrp
    int mb = mgrp * 3;                           // 3 M-tiles (48 ch) per wave

    f32x4 acc[3][4];
#pragma unroll
    for (int i = 0; i < 3; ++i)
#pragma unroll
        for (int j = 0; j < 4; ++j) acc[i][j] = f32x4{0.f, 0.f, 0.f, 0.f};

    // per-lane weight fragment base (fragment-major layout)
    const unsigned short* wfb = Wt2 + (size_t)lane * 8;

    for (int kc2 = 0; kc2 < 2; ++kc2) {          // two 64-channel K chunks
        if (kc2) __syncthreads();                // all tap reads of sa done
        // stage act: rows h0-1..h0+4, 64 w, 64 ch (3072 uint4)
#pragma unroll
        for (int j = 0; j < 6; ++j) {
            int idx = j * 512 + t;
            int row = idx >> 9, rem = idx & 511;
            int w = rem >> 3, c0 = (rem & 7) * 8;
            int gh = h0 - 1 + row;
            uint4 v = uint4{0, 0, 0, 0};
            if (gh >= 0 && gh < 64)
                v = *reinterpret_cast<const uint4*>(
                    hbuf + (((size_t)b * 64 + gh) * 64 + w) * 128 + kc2 * 64 + c0);
            *reinterpret_cast<uint4*>(&sa[(row * 66 + (w + 1)) * LWA + c0]) = v;
        }
        if (t < 96) {                            // zero halo cols 0 and 65
            int row = t >> 4, k = t & 15;
            int col = (k & 1) ? 65 : 0, c0 = (k >> 1) * 8;
            *reinterpret_cast<uint4*>(&sa[(row * 66 + col) * LWA + c0]) = uint4{0, 0, 0, 0};
        }
        __syncthreads();                         // act visible

#pragma unroll
        for (int tap = 0; tap < 9; ++tap) {
            int s = kc2 * 9 + tap;
            const unsigned short* wsl = wfb + (size_t)s * 6144;
            int dh = tap / 3, dw = tap % 3;
            bf16x8 wfr[3][2];
#pragma unroll
            for (int mi = 0; mi < 3; ++mi) {
                int ot = mb + mi;
                wfr[mi][0] = *reinterpret_cast<const bf16x8*>(wsl + (size_t)(ot * 2 + 0) * 512);
                wfr[mi][1] = *reinterpret_cast<const bf16x8*>(wsl + (size_t)(ot * 2 + 1) * 512);
            }
#pragma unroll
            for (int ni = 0; ni < 4; ++ni) {
                int nt = ngrp * 4 + ni;
                int rr = nt >> 2, wcol = (nt & 3) * 16 + lrow;
                int base = ((rr + dh) * 66 + wcol + dw) * LWA;
                bf16x8 a0 = *reinterpret_cast<const bf16x8*>(&sa[base + kgrp * 8]);
                bf16x8 a1 = *reinterpret_cast<const bf16x8*>(&sa[base + 32 + kgrp * 8]);
#pragma unroll
                for (int mi = 0; mi < 3; ++mi) {
                    acc[mi][ni] = __builtin_amdgcn_mfma_f32_16x16x32_bf16(wfr[mi][0], a0, acc[mi][ni], 0, 0, 0);
                    acc[mi][ni] = __builtin_amdgcn_mfma_f32_16x16x32_bf16(wfr[mi][1], a1, acc[mi][ni], 0, 0, 0);
                }
            }
        }
    }

    // ---- epilogue: two 128-position halves (params f32 aliased over sa) ----
    float lad_acc = 0.f;
    for (int half = 0; half < 2; ++half) {
        __syncthreads();                         // acc done / prev-half spline reads done
        if ((ngrp >> 1) == half) {               // ngrp {0,1}->half0, {2,3}->half1
#pragma unroll
            for (int mi = 0; mi < 3; ++mi) {
                int o0 = (mb + mi) * 16 + kgrp * 4;
                float bb0 = b2[o0], bb1 = b2[o0 + 1], bb2 = b2[o0 + 2], bb3 = b2[o0 + 3];
#pragma unroll
                for (int ni = 0; ni < 4; ++ni) {
                    int p = (ngrp & 1) * 64 + ni * 16 + lrow;   // 0..127 within half
                    f32x4 v = acc[mi][ni];
                    pm[p * 101 + o0]     = v[0] + bb0;
                    pm[p * 101 + o0 + 1] = v[1] + bb1;
                    pm[p * 101 + o0 + 2] = v[2] + bb2;
                    pm[p * 101 + o0 + 3] = v[3] + bb3;
                }
            }
        }
        __syncthreads();
        // spline: 128 pos x 32 spline-ch = 4096 elems, 512 thr x 8 iters
#pragma unroll 4
        for (int it = 0; it < 8; ++it) {
            int idx = it * 512 + t;
            int c = idx >> 7, p = idx & 127;
            int pos = half * 128 + p;
            int pb = p * 101 + 3 * c;
            float u0 = pm[pb];
            float u1 = pm[pb + 1];
            float u2 = pm[pb + 2];
            size_t gpos = (size_t)(b * 64 + 32 + c) * 4096 + (size_t)(h0 + (pos >> 6)) * 64 + (pos & 63);
            float xin = x[gpos];
            float mx = fmaxf(u0, fmaxf(u1, u2));
            float e0 = __expf(u0 - mx), e1 = __expf(u1 - mx), e2 = __expf(u2 - mx);
            float s = e0 + e1 + e2;
            float inv = 1.0f / s;
            float pos01 = fminf(fmaxf((xin + 1.f) * 0.5f, 0.f), 1.f) * 3.f;
            int bin = (int)pos01; bin = bin > 2 ? 2 : bin;
            float alpha = pos01 - (float)bin;
            float eb = (bin == 0) ? e0 : ((bin == 1) ? e1 : e2);
            float cb = (bin == 0) ? 0.f : ((bin == 1) ? e0 : (e0 + e1));
            float pk = eb * inv;
            float outv = cb * inv + alpha * pk;
            outv = fminf(fmaxf(outv, 0.f), 1.f) * 2.f - 1.f;
            float lad = __logf(pk) + 1.09861228866810969f;   // + log(3)
            bool inside = (xin >= -1.f) && (xin <= 1.f);
            if (!inside) { outv = xin; lad = 0.f; }
            out[gpos] = outv;
            lad_acc += lad;
        }
    }
#pragma unroll
    for (int off = 32; off > 0; off >>= 1)
        lad_acc += __shfl_down(lad_acc, off, 64);
    if (lane == 0) red[wid] = lad_acc;
    __syncthreads();
    if (t == 0) {
        float s = 0.f;
#pragma unroll
        for (int i = 0; i < 8; ++i) s += red[i];
        atomicAdd(out + 8388608 + b, s);
    }
}

extern "C" void kernel_launch(void* const* d_in, const int* in_sizes, int n_in,
                              void* d_out, int out_size, void* d_ws, size_t ws_size,
                              hipStream_t stream) {
    const float* x   = (const float*)d_in[0];
    const float* obj = (const float*)d_in[1];
    const float* W1  = (const float*)d_in[2];
    const float* b1  = (const float*)d_in[3];
    const float* W2  = (const float*)d_in[4];
    const float* b2  = (const float*)d_in[5];
    float* out = (float*)d_out;
    char* ws = (char*)d_ws;

    unsigned short* hbuf = (unsigned short*)ws;                  // 33,554,432 B
    unsigned short* Wt1  = (unsigned short*)(ws + 33554432);     //     73,728 B
    unsigned short* Wt2  = (unsigned short*)(ws + 33554432 + 73728); // 221,184 B

    hipLaunchKernelGGL(prep_w,       dim3(432), dim3(256), 0, stream, W1, W2, Wt1, Wt2);
    hipLaunchKernelGGL(conv1_fused,  dim3(512), dim3(256), 0, stream, x, obj, b1, Wt1, hbuf, out);
    hipLaunchKernelGGL(conv2_spline, dim3(512), dim3(512), 0, stream, hbuf, b2, Wt2, x, out);
}